// Round 13
// baseline (2783.795 us; speedup 1.0000x reference)
//
#include <hip/hip_runtime.h>
#include <math.h>

#define NN 50000
#define TT 4
#define FF 128
#define EE 800000
#define NSEG 4      // node-space segments for LDS deg histogram
#define BINSEG 12500
#define NCH 32      // edge chunks for deg histogram
#define CHUNK 25000
#define NCH2 128    // edge chunks for partition
#define CH2 6250    // EE/NCH2
#define NB2 64      // coarse dst buckets
#define CB 782      // nodes per bucket (64*782=50048 >= NN)
#define NSEG2 16    // src segments for within-row quantile sort
#define SEGW 3125   // 50000/16
#define SBINS (CB*NSEG2)   // 12512
#define SCHUNK 49          // ceil(SBINS/256)
#define SMAX 13312  // LDS sort capacity per bucket (mean 12512, +7 sigma; 52 KB)
#define SPB 2048    // spmm blocks (multiple of 8; 8/CU)

typedef __attribute__((ext_vector_type(8))) short bf8_t;
typedef __attribute__((ext_vector_type(4))) float f4_t;
typedef __attribute__((ext_vector_type(8))) ushort us8;

__device__ inline ushort f2bf(float f){
  union { float f; unsigned u; } v; v.f = f;
  unsigned u = v.u;
  unsigned r = (u + 0x7fff + ((u>>16)&1)) >> 16;  // RNE
  return (ushort)r;
}
__device__ inline float lo16(unsigned u){ union{unsigned u;float f;}v; v.u=u<<16; return v.f; }
__device__ inline float hi16(unsigned u){ union{unsigned u;float f;}v; v.u=u&0xffff0000u; return v.f; }
__device__ inline unsigned packbf(float x, float y){
  return (unsigned)f2bf(x) | ((unsigned)f2bf(y)<<16);
}
__device__ inline float sigm(float x){ return 1.f/(1.f+expf(-x)); }

// Quarter-major activation layout: X[q][n][32] bf16 (q = feature/32).
// element (n,f) at ushort index ((f>>5)*NN + n)*32 + (f&31).

// ---------------- utility ----------------
// cast all T snapshots to quarter-major bf16
__global__ void k_cast4(const float* __restrict__ in, ushort* __restrict__ outp, int n4){
  int i = blockIdx.x*256 + threadIdx.x;
  if(i<n4){
    float4 v = ((const float4*)in)[i];
    ushort4 o; o.x=f2bf(v.x); o.y=f2bf(v.y); o.z=f2bf(v.z); o.w=f2bf(v.w);
    int t = i / (NN*32);
    int rem = i - t*(NN*32);
    int r = rem >> 5;
    int f = (rem & 31) * 4;
    *(ushort4*)(outp + (size_t)t*NN*128 + ((size_t)(f>>5)*NN + r)*32 + (f&31)) = o;
  }
}
__global__ void k_bias(const float* bxz, const float* bhz, const float* bxr,
                       const float* bhr, const float* bxh, const float* bhh,
                       float* __restrict__ bz, float* __restrict__ br, float* __restrict__ bh){
  int i = threadIdx.x;  // 384 threads
  int c = i & 127, s = i >> 7;
  if(s==0) bz[c]=bxz[c]+bhz[c];
  else if(s==1) br[c]=bxr[c]+bhr[c];
  else bh[c]=bxh[c]+bhh[c];
}

// ---------- deg (src) histogram via LDS segments -> dinv ----------
__global__ __launch_bounds__(256) void k_hist(const int* __restrict__ ei,
                                              int* __restrict__ part){
  int c = blockIdx.x, seg = blockIdx.y, t = blockIdx.z;
  const int* keys = ei + (size_t)t*2*EE;   // src array
  __shared__ int h[BINSEG];
  for(int i=threadIdx.x;i<BINSEG;i+=256) h[i]=0;
  __syncthreads();
  int base = seg*BINSEG;
  int e0 = c*CHUNK, e1 = e0+CHUNK;
  for(int e=e0+threadIdx.x; e<e1; e+=256){
    int k = keys[e] - base;
    if((unsigned)k < (unsigned)BINSEG) atomicAdd(&h[k],1);
  }
  __syncthreads();
  int* dp = part + ((((size_t)t)*NSEG + seg)*NCH + c)*BINSEG;
  for(int i=threadIdx.x;i<BINSEG;i+=256) dp[i]=h[i];
}
__global__ void k_merge(const int* __restrict__ part, float* __restrict__ dinv4){
  int t = blockIdx.y;
  int n = blockIdx.x*256 + threadIdx.x;
  if(n>=NN) return;
  int seg = n / BINSEG, b = n - seg*BINSEG;
  const int* p = part + ((((size_t)t)*NSEG + seg)*NCH)*BINSEG + b;
  int s = 0;
  #pragma unroll
  for(int c=0;c<NCH;++c) s += p[(size_t)c*BINSEG];
  dinv4[(size_t)t*NN + n] = s>0 ? rsqrtf((float)s) : 0.f;
}

// ---------- coarse bucket counts per (t, chunk) ----------
__global__ __launch_bounds__(256) void k_ccount(const int* __restrict__ ei,
                                                int* __restrict__ ccnt){
  int c = blockIdx.x, t = blockIdx.y;
  const int* dst = ei + (size_t)t*2*EE + EE;
  __shared__ int h[NB2];
  if(threadIdx.x<NB2) h[threadIdx.x]=0;
  __syncthreads();
  int e0 = c*CH2, e1 = e0+CH2;
  for(int e=e0+threadIdx.x; e<e1; e+=256) atomicAdd(&h[dst[e]/CB],1);
  __syncthreads();
  if(threadIdx.x<NB2) ccnt[((size_t)t*NB2 + threadIdx.x)*NCH2 + c] = h[threadIdx.x];
}
__global__ __launch_bounds__(128) void k_cscan(const int* __restrict__ ccnt,
                        int* __restrict__ Abase, int* __restrict__ Bbase,
                        int* __restrict__ tot){
  int t = blockIdx.x, tid = threadIdx.x;
  __shared__ int st[NB2];
  __shared__ int sb[NB2];
  const int* cc = ccnt + (size_t)t*NB2*NCH2;
  if(tid<NB2){
    int s=0;
    for(int c=0;c<NCH2;++c) s += cc[tid*NCH2+c];
    st[tid]=s;
  }
  __syncthreads();
  if(tid==0){
    int run=0;
    for(int b=0;b<NB2;++b){ sb[b]=run; run+=st[b]; }
  }
  __syncthreads();
  if(tid<NB2){
    Bbase[t*NB2+tid]=sb[tid];
    tot[t*NB2+tid]=st[tid];
    int run = sb[tid];
    int* ab = Abase + ((size_t)t*NB2 + tid)*NCH2;
    for(int c=0;c<NCH2;++c){ ab[c]=run; run+=cc[tid*NCH2+c]; }
  }
}
__global__ __launch_bounds__(256) void k_part(const int* __restrict__ ei,
                        const int* __restrict__ Abase, unsigned* __restrict__ staging){
  int c = blockIdx.x, t = blockIdx.y;
  const int* src = ei + (size_t)t*2*EE;
  const int* dst = src + EE;
  unsigned* stg = staging + (size_t)t*EE;
  const int* ab = Abase + (size_t)t*NB2*NCH2;
  __shared__ int h[NB2];
  if(threadIdx.x<NB2) h[threadIdx.x]=0;
  __syncthreads();
  int e0 = c*CH2, e1 = e0+CH2;
  for(int e=e0+threadIdx.x; e<e1; e+=256){
    int s=src[e], d=dst[e];
    int b = d/CB, dl = d - b*CB;
    int r = atomicAdd(&h[b],1);
    stg[ab[b*NCH2 + c] + r] = ((unsigned)dl<<16) | (unsigned)s;
  }
}
// per-bucket LDS counting sort by (dstLocal, src/SEGW) -> meta + offs
__global__ __launch_bounds__(256) void k_sortb(const unsigned* __restrict__ staging,
                        const int* __restrict__ Bbase, const int* __restrict__ tot,
                        const float* __restrict__ dinv4, int2* __restrict__ meta4,
                        int* __restrict__ offs4){
  int b = blockIdx.x, t = blockIdx.y, tid = threadIdx.x;
  __shared__ int cnt[SBINS];
  __shared__ int sums[256];
  __shared__ unsigned sorted[SMAX];
  int sA = Bbase[t*NB2+b];
  int nb = tot[t*NB2+b];
  const unsigned* stg = staging + (size_t)t*EE + sA;
  const float* dinv = dinv4 + (size_t)t*NN;
  int* offs = offs4 + (size_t)t*(NN+1);
  int2* meta = meta4 + (size_t)t*EE + sA;
  for(int i=tid;i<SBINS;i+=256) cnt[i]=0;
  __syncthreads();
  for(int i=tid;i<nb;i+=256){
    unsigned v = stg[i];
    int key = (int)(v>>16)*NSEG2 + (int)(v&0xFFFF)/SEGW;
    atomicAdd(&cnt[key],1);
  }
  __syncthreads();
  int base = tid*SCHUNK;
  int s0 = 0;
  for(int j=0;j<SCHUNK;++j){ int idx=base+j; if(idx<SBINS) s0+=cnt[idx]; }
  sums[tid]=s0; __syncthreads();
  for(int off=1;off<256;off<<=1){
    int v=(tid>=off)?sums[tid-off]:0; __syncthreads();
    sums[tid]+=v; __syncthreads();
  }
  int run = sums[tid]-s0;
  for(int j=0;j<SCHUNK;++j){
    int idx=base+j;
    if(idx<SBINS){ int c=cnt[idx]; cnt[idx]=run; run+=c; }
  }
  __syncthreads();
  for(int dl=tid; dl<CB; dl+=256){
    int n = b*CB + dl;
    if(n<=NN) offs[n] = sA + cnt[dl*NSEG2];
  }
  __syncthreads();
  for(int i=tid;i<nb;i+=256){
    unsigned v = stg[i];
    int key = (int)(v>>16)*NSEG2 + (int)(v&0xFFFF)/SEGW;
    int r = atomicAdd(&cnt[key],1);
    if(r<SMAX) sorted[r]=v;
  }
  __syncthreads();
  for(int i=tid;i<nb;i+=256){
    if(i>=SMAX) break;
    unsigned v = sorted[i];
    int s = v & 0xFFFF, d = b*CB + (v>>16);
    int2 m; m.x = s; m.y = __float_as_int(-dinv[s]*dinv[d]);
    meta[i]=m;
  }
}

// -------- quarter-split single-input gather-SpMM, XCD-pinned quarters --------
// q = (blockIdx&7)>>1: each XCD pair serves one 3.2 MB quarter (fits 4 MB L2).
// Wave = 4 groups x 16 lanes, ALL on the SAME row; group g takes edges e==g mod 4;
// shfl_xor(16/32) reduces partials. meta via nontemporal load, outputs via
// nontemporal store so streams don't evict the resident gather table.
__global__ __launch_bounds__(256) void k_spmm1q(const int* __restrict__ offs,
                        const int2* __restrict__ meta,
                        const ushort* __restrict__ Xa, ushort* __restrict__ outA){
  int bid = blockIdx.x;
  int q = (bid & 7) >> 1;
  int rank = ((bid >> 3) << 1) | (bid & 1);   // 0..SPB/4-1
  int wid = threadIdx.x >> 6;
  int waveIdx = rank*4 + wid;                 // 0..(SPB-1)
  int g = (threadIdx.x >> 4) & 3;
  int l = threadIdx.x & 15;
  const unsigned* XA = (const unsigned*)Xa + (size_t)q*NN*16;
  unsigned* OA = (unsigned*)outA + (size_t)q*NN*16;
  const long long* mp = (const long long*)meta;
  for(int row = waveIdx; row < NN; row += SPB){
    int beg = offs[row], end = offs[row+1];
    float ax=0.f, ay=0.f;
    for(int e = beg + g; e < end; e += 4){
      long long mv = __builtin_nontemporal_load(mp + e);
      int s = (int)(unsigned)(mv & 0xffffffffLL);
      float w = __int_as_float((int)(mv >> 32));
      unsigned a = XA[(size_t)s*16 + l];
      ax = fmaf(w, lo16(a), ax);
      ay = fmaf(w, hi16(a), ay);
    }
    ax += __shfl_xor(ax, 16); ax += __shfl_xor(ax, 32);
    ay += __shfl_xor(ay, 16); ay += __shfl_xor(ay, 32);
    if(g==0) __builtin_nontemporal_store(packbf(ax, ay), OA + (size_t)row*16 + l);
  }
}

// ---------------- MFMA bf16 GEMM (A operands quarter-major) ----------------
// modes: 0 = fp32 store Cf[r*384+coloff+c]  (GRU main)
//        1 = fp32 beta-accumulate Cf[r*384+coloff+c]  (HR path)
//        2 = bias+relu -> bf16 Cb quarter-major  (decoder 1)
//        3 = bias -> fp32 Cf[r*128+c]       (decoder 2)
__global__ __launch_bounds__(256) void k_mgemm(
    const ushort* __restrict__ A0, const ushort* __restrict__ A1,
    const ushort* __restrict__ A2, const ushort* __restrict__ A3,
    const ushort* __restrict__ A4, const ushort* __restrict__ A5,
    const ushort* __restrict__ Bt, ushort* __restrict__ Cb, float* __restrict__ Cf,
    int K, int ldb, int ngrp, int bnstep, int coloff, int mode, int nwg,
    const float* __restrict__ bias)
{
  __shared__ ushort As[128*64];
  __shared__ ushort Bs[128*64];
  int tid = threadIdx.x;
  int lane = tid & 63;
  int wid = tid >> 6;
  int wr = (wid>>1)*64, wc = (wid&1)*64;
  int bid = blockIdx.x;
  int q = nwg >> 3, r = nwg & 7;
  int xs = bid & 7, j = bid >> 3;
  int logical = xs*q + ((xs<r)?xs:r) + j;
  int bm = logical / ngrp;
  int bn = (logical - bm*ngrp) * bnstep;
  f4_t acc[4][4] = {};
  int srow = tid>>3, sc = tid&7;
  int lr = lane&15, lk = lane>>4;
  int nkt = K>>6;
  for(int kt=0; kt<nkt; ++kt){
    int k0 = kt<<6;
    const ushort* Ac = (k0<128)?A0:(k0<256)?A1:(k0<384)?A2:(k0<512)?A3:(k0<640)?A4:A5;
    int kloc = k0 & 127;
    int f0 = kloc + sc*8;  // 8 contiguous features within one quarter
    size_t aoff = ((size_t)(f0>>5)*NN)*32 + (f0&31);
    #pragma unroll
    for(int p=0;p<4;++p){
      int rr = srow + p*32;
      int gr = bm*128 + rr; if(gr>=NN) gr=NN-1;
      us8 av = *(const us8*)(Ac + aoff + (size_t)gr*32);
      us8 bv = *(const us8*)(Bt + (size_t)(bn*128 + rr)*ldb + k0 + sc*8);
      int wo = (rr*128 + ((sc*16) ^ ((rr&7)<<4))) >> 1;
      *(us8*)(As + wo) = av;
      *(us8*)(Bs + wo) = bv;
    }
    __syncthreads();
    #pragma unroll
    for(int kk=0;kk<2;++kk){
      bf8_t af[4], bfr[4];
      int co = kk*64 + lk*16;
      #pragma unroll
      for(int m=0;m<4;++m){
        int Ra = wr + m*16 + lr;
        af[m]  = *(const bf8_t*)(As + ((Ra*128 + (co ^ ((Ra&7)<<4)))>>1));
        int Rb = wc + m*16 + lr;
        bfr[m] = *(const bf8_t*)(Bs + ((Rb*128 + (co ^ ((Rb&7)<<4)))>>1));
      }
      #pragma unroll
      for(int m=0;m<4;++m)
        #pragma unroll
        for(int n=0;n<4;++n)
          acc[m][n] = __builtin_amdgcn_mfma_f32_16x16x32_bf16(af[m], bfr[n], acc[m][n], 0,0,0);
    }
    __syncthreads();
  }
  int row0 = bm*128 + wr + lk*4;
  int col0 = bn*128 + wc + lr;
  #pragma unroll
  for(int m=0;m<4;++m){
    #pragma unroll
    for(int i=0;i<4;++i){
      int rI = row0 + m*16 + i;
      if(rI<NN){
        if(mode<=1){
          float* cp = Cf + (size_t)rI*384 + coloff + col0;
          #pragma unroll
          for(int n=0;n<4;++n){
            float v = acc[m][n][i];
            if(mode==1) v += cp[n*16];
            cp[n*16] = v;
          }
        } else if(mode==2){
          #pragma unroll
          for(int n=0;n<4;++n){
            int c = col0 + n*16;
            float v = acc[m][n][i] + bias[c];
            Cb[((size_t)(c>>5)*NN + rI)*32 + (c&31)] = f2bf(fmaxf(v,0.f));
          }
        } else {
          #pragma unroll
          for(int n=0;n<4;++n){
            int c = col0 + n*16;
            Cf[(size_t)rI*128 + c] = acc[m][n][i] + bias[c];
          }
        }
      }
    }
  }
}

// Z = sigmoid(OX[:,0:128]+bz); HRb(qm) = bf16(H * sigmoid(OX[:,128:256]+br))
__global__ void k_combA(const float* __restrict__ OX, const float* __restrict__ H,
                        const float* __restrict__ bz, const float* __restrict__ br,
                        float* __restrict__ Z, ushort* __restrict__ HRb){
  int i = blockIdx.x*256 + threadIdx.x;
  if(i>=NN*FF) return;
  int r = i>>7, c = i&127;
  float zv = sigm(OX[r*384+c]     + bz[c]);
  float rv = sigm(OX[r*384+128+c] + br[c]);
  float hr = H[i]*rv;
  Z[i]=zv;
  HRb[((size_t)(c>>5)*NN + r)*32 + (c&31)] = f2bf(hr);
}
// Htilde = tanh(OX[:,256:384]+bh); Hnew = Z*H + (1-Z)*Htilde; Hnb quarter-major
__global__ void k_combB(const float* __restrict__ OX, const float* __restrict__ Z,
                        const float* __restrict__ H, const float* __restrict__ bh,
                        float* __restrict__ Hn, ushort* __restrict__ Hnb,
                        float* __restrict__ Hout2){
  int i = blockIdx.x*256 + threadIdx.x;
  if(i>=NN*FF) return;
  int r = i>>7, c = i&127;
  float ht = tanhf(OX[r*384+256+c] + bh[c]);
  float z = Z[i];
  float hn = z*H[i] + (1.f-z)*ht;
  Hn[i] = hn;
  Hnb[((size_t)(c>>5)*NN + r)*32 + (c&31)] = f2bf(hn);
  if(Hout2) Hout2[i] = hn;
}
// t=0 (H==0): Hn = (1 - sigm(OXz+bz)) * tanh(OXh+bh)
__global__ void k_gru0(const float* __restrict__ OX, const float* __restrict__ bz,
                       const float* __restrict__ bh, float* __restrict__ Hn,
                       ushort* __restrict__ Hnb){
  int i = blockIdx.x*256 + threadIdx.x;
  if(i>=NN*FF) return;
  int r = i>>7, c = i&127;
  float z  = sigm(OX[r*384+c] + bz[c]);
  float ht = tanhf(OX[r*384+256+c] + bh[c]);
  float hn = (1.f - z)*ht;
  Hn[i]=hn;
  Hnb[((size_t)(c>>5)*NN + r)*32 + (c&31)] = f2bf(hn);
}

// pack x-side weights, REBASED: chunks [X:(W0-W2), U1:W1, U2:2*W2]
__global__ void k_packx(const float* __restrict__ Wxz, const float* __restrict__ Wxr,
                        const float* __restrict__ Wxh, const float* __restrict__ Whz,
                        const float* __restrict__ Whr, ushort* __restrict__ Bt){
  int i = blockIdx.x*256 + threadIdx.x;
  if(i>=384*768) return;
  int c = i/768, k = i - c*768;
  int g = c>>7, j = c&127;
  int kb = k>>7, kk = k&127;
  float v;
  int e = kk*128 + j;
  if(kb<3){
    const float* W = (g==0)?Wxz:((g==1)?Wxr:Wxh);
    v = (kb==0) ? (W[e] - W[2*16384 + e]) : (kb==1 ? W[16384 + e] : 2.f*W[2*16384 + e]);
  } else if(g<2){
    const float* W = (g==0)?Whz:Whr;
    int kb2 = kb-3;
    v = (kb2==0) ? (W[e] - W[2*16384 + e]) : (kb2==1 ? W[16384 + e] : 2.f*W[2*16384 + e]);
  } else v = 0.f;
  Bt[i] = f2bf(v);
}
__global__ void k_packh(const float* __restrict__ Whh, ushort* __restrict__ Bt){
  int i = blockIdx.x*256 + threadIdx.x;
  if(i>=128*384) return;
  int c = i/384, k = i - c*384;
  int kb = k>>7, kk = k&127;
  int e = kk*128 + c;
  float v = (kb==0) ? (Whh[e] - Whh[2*16384 + e]) : (kb==1 ? Whh[16384 + e] : 2.f*Whh[2*16384 + e]);
  Bt[i] = f2bf(v);
}
// decoder weight: Bt[c][k] = W[k][c], 128x128
__global__ void k_packd(const float* __restrict__ W, ushort* __restrict__ Bt){
  int i = blockIdx.x*256 + threadIdx.x;
  if(i>=128*128) return;
  int c = i>>7, k = i&127;
  Bt[i] = f2bf(W[k*128 + c]);
}

extern "C" void kernel_launch(void* const* d_in, const int* in_sizes, int n_in,
                              void* d_out, int out_size, void* d_ws, size_t ws_size,
                              hipStream_t stream) {
  const float* x   = (const float*)d_in[0];
  const int*   ei  = (const int*)d_in[1];
  const float* Wxz = (const float*)d_in[2];
  const float* Whz = (const float*)d_in[3];
  const float* Wxr = (const float*)d_in[4];
  const float* Whr = (const float*)d_in[5];
  const float* Wxh = (const float*)d_in[6];
  const float* Whh = (const float*)d_in[7];
  const float* bxz = (const float*)d_in[8];
  const float* bhz = (const float*)d_in[9];
  const float* bxr = (const float*)d_in[10];
  const float* bhr = (const float*)d_in[11];
  const float* bxh = (const float*)d_in[12];
  const float* bhh = (const float*)d_in[13];
  const float* Wd1 = (const float*)d_in[14];
  const float* bd1 = (const float*)d_in[15];
  const float* Wd2 = (const float*)d_in[16];
  const float* bd2 = (const float*)d_in[17];
  float* out = (float*)d_out;

  char* p = (char*)d_ws;
  auto alloc = [&](size_t bytes)->void*{ void* r = (void*)p; p += (bytes+255)&~(size_t)255; return r; };
  const size_t NFB  = (size_t)NN*FF*4;
  const size_t NFB2 = (size_t)NN*FF*2;
  float* Ha   = (float*)alloc(NFB);
  float* Hb   = (float*)alloc(NFB);
  float* OX   = (float*)alloc((size_t)NN*384*4);
  float* Zb   = (float*)alloc(NFB);
  ushort* xtb4= (ushort*)alloc(NFB2*TT);
  ushort* A1b = (ushort*)alloc(NFB2);
  ushort* A2b = (ushort*)alloc(NFB2);
  ushort* A3b = (ushort*)alloc(NFB2);
  ushort* A4b = (ushort*)alloc(NFB2);
  ushort* HRb = (ushort*)alloc(NFB2);
  ushort* Hab = (ushort*)alloc(NFB2);
  ushort* Hbb = (ushort*)alloc(NFB2);
  ushort* Btx = (ushort*)alloc((size_t)384*768*2);
  ushort* Bth = (ushort*)alloc((size_t)128*384*2);
  ushort* Btd1= (ushort*)alloc((size_t)128*128*2);
  ushort* Btd2= (ushort*)alloc((size_t)128*128*2);
  float* bzc  = (float*)alloc(128*4);
  float* brc  = (float*)alloc(128*4);
  float* bhc  = (float*)alloc(128*4);
  float* dinv4= (float*)alloc((size_t)TT*NN*4);
  int* ccnt   = (int*)alloc((size_t)TT*NB2*NCH2*4);
  int* Abase  = (int*)alloc((size_t)TT*NB2*NCH2*4);
  int* Bbase  = (int*)alloc((size_t)TT*NB2*4);
  int* tot    = (int*)alloc((size_t)TT*NB2*4);
  int* offs4  = (int*)alloc((size_t)TT*(NN+1)*4);
  int2* meta4 = (int2*)alloc((size_t)TT*EE*8);
  // aliases consumed before GRU loop: deg partials in Ha (25.6MB), staging in Hb (12.8MB)
  int* partial = (int*)Ha;
  unsigned* staging = (unsigned*)Hb;

  const int fb = (NN*FF+255)/256;
  const int MT = (NN+127)/128;      // 391

  // ---- one-time prep ----
  k_packx<<<(384*768+255)/256,256,0,stream>>>(Wxz,Wxr,Wxh,Whz,Whr,Btx);
  k_packh<<<(128*384+255)/256,256,0,stream>>>(Whh,Bth);
  k_packd<<<64,256,0,stream>>>(Wd1,Btd1);
  k_packd<<<64,256,0,stream>>>(Wd2,Btd2);
  k_bias<<<1,384,0,stream>>>(bxz,bhz,bxr,bhr,bxh,bhh,bzc,brc,bhc);
  k_cast4<<<(TT*NN*FF/4+255)/256,256,0,stream>>>(x, xtb4, TT*NN*FF/4);
  dim3 gh(NCH, NSEG, TT);
  k_hist<<<gh,256,0,stream>>>(ei, partial);
  dim3 gm((NN+255)/256, TT);
  k_merge<<<gm,256,0,stream>>>(partial, dinv4);
  dim3 gc(NCH2, TT);
  k_ccount<<<gc,256,0,stream>>>(ei, ccnt);
  k_cscan<<<TT,128,0,stream>>>(ccnt, Abase, Bbase, tot);
  k_part<<<gc,256,0,stream>>>(ei, Abase, staging);
  dim3 gs(NB2, TT);
  k_sortb<<<gs,256,0,stream>>>(staging, Bbase, tot, dinv4, meta4, offs4);

  float* Hc = Ha; float* Hn = Hb;
  ushort* Hcb = Hab; ushort* Hnb = Hbb;
  for(int t=0;t<TT;++t){
    const ushort* xtb = xtb4 + (size_t)t*NN*FF;
    const int* offs = offs4 + (size_t)t*(NN+1);
    const int2* meta = meta4 + (size_t)t*EE;
    if(t==0){
      k_spmm1q<<<SPB,256,0,stream>>>(offs,meta, xtb, A1b);
      k_spmm1q<<<SPB,256,0,stream>>>(offs,meta, A1b, A2b);
      int nwg0 = MT*2;
      k_mgemm<<<nwg0,256,0,stream>>>(xtb,A1b,A2b,nullptr,nullptr,nullptr,
          Btx, nullptr, OX, 384, 768, 2, 2, 0, 0, nwg0, nullptr);
      k_gru0<<<fb,256,0,stream>>>(OX, bzc, bhc, Hn, Hnb);
    } else {
      k_spmm1q<<<SPB,256,0,stream>>>(offs,meta, xtb, A1b);
      k_spmm1q<<<SPB,256,0,stream>>>(offs,meta, Hcb, A3b);
      k_spmm1q<<<SPB,256,0,stream>>>(offs,meta, A1b, A2b);
      k_spmm1q<<<SPB,256,0,stream>>>(offs,meta, A3b, A4b);
      int nwg1 = MT*3;
      k_mgemm<<<nwg1,256,0,stream>>>(xtb,A1b,A2b,Hcb,A3b,A4b,
          Btx, nullptr, OX, 768, 768, 3, 1, 0, 0, nwg1, nullptr);
      k_combA<<<fb,256,0,stream>>>(OX,Hc,bzc,brc,Zb,HRb);
      k_spmm1q<<<SPB,256,0,stream>>>(offs,meta, HRb, A3b);
      k_spmm1q<<<SPB,256,0,stream>>>(offs,meta, A3b, A4b);
      int nwg3 = MT;
      k_mgemm<<<nwg3,256,0,stream>>>(HRb,A3b,A4b,nullptr,nullptr,nullptr,
          Bth, nullptr, OX, 384, 384, 1, 1, 256, 1, nwg3, nullptr);
      float* hout2 = (t==TT-1) ? (out + (size_t)NN*FF) : nullptr;
      k_combB<<<fb,256,0,stream>>>(OX,Zb,Hc,bhc,Hn,Hnb,hout2);
    }
    float* tmp=Hc; Hc=Hn; Hn=tmp;
    ushort* tb=Hcb; Hcb=Hnb; Hnb=tb;
  }
  // decoder: relu(H@Wd1+bd1)@Wd2+bd2  (MFMA bf16; A1b as quarter-major temp)
  k_mgemm<<<MT,256,0,stream>>>(Hcb,nullptr,nullptr,nullptr,nullptr,nullptr,
      Btd1, A1b, nullptr, 128, 128, 1, 1, 0, 2, MT, bd1);
  k_mgemm<<<MT,256,0,stream>>>(A1b,nullptr,nullptr,nullptr,nullptr,nullptr,
      Btd2, nullptr, out, 128, 128, 1, 1, 0, 3, MT, bd2);
}

// Round 14
// 1818.606 us; speedup vs baseline: 1.5307x; 1.5307x over previous
//
#include <hip/hip_runtime.h>
#include <math.h>

#define NN 50000
#define TT 4
#define FF 128
#define EE 800000
#define NSEG 4      // node-space segments for LDS deg histogram
#define BINSEG 12500
#define NCH 32      // edge chunks for deg histogram
#define CHUNK 25000
#define NCH2 128    // edge chunks for partition
#define CH2 6250    // EE/NCH2
#define NB2 64      // coarse dst buckets
#define CB 782      // nodes per bucket (64*782=50048 >= NN)
#define NSEG2 16    // src segments for within-row quantile sort
#define SEGW 3125   // 50000/16
#define SBINS (CB*NSEG2)   // 12512
#define SCHUNK 49          // ceil(SBINS/256)
#define SMAX 13312  // LDS sort capacity per bucket (mean 12512, +7 sigma; 52 KB)
#define SPB 2048    // spmm blocks (multiple of 8; 8/CU)

typedef __attribute__((ext_vector_type(8))) short bf8_t;
typedef __attribute__((ext_vector_type(4))) float f4_t;
typedef __attribute__((ext_vector_type(8))) ushort us8;

__device__ inline ushort f2bf(float f){
  union { float f; unsigned u; } v; v.f = f;
  unsigned u = v.u;
  unsigned r = (u + 0x7fff + ((u>>16)&1)) >> 16;  // RNE
  return (ushort)r;
}
__device__ inline float lo16(unsigned u){ union{unsigned u;float f;}v; v.u=u<<16; return v.f; }
__device__ inline float hi16(unsigned u){ union{unsigned u;float f;}v; v.u=u&0xffff0000u; return v.f; }
__device__ inline unsigned packbf(float x, float y){
  return (unsigned)f2bf(x) | ((unsigned)f2bf(y)<<16);
}
__device__ inline float sigm(float x){ return 1.f/(1.f+expf(-x)); }

// Quarter-major activation layout: X[q][n][32] bf16 (q = feature/32).
// element (n,f) at ushort index ((f>>5)*NN + n)*32 + (f&31).

// ---------------- utility ----------------
// cast all T snapshots to quarter-major bf16
__global__ void k_cast4(const float* __restrict__ in, ushort* __restrict__ outp, int n4){
  int i = blockIdx.x*256 + threadIdx.x;
  if(i<n4){
    float4 v = ((const float4*)in)[i];
    ushort4 o; o.x=f2bf(v.x); o.y=f2bf(v.y); o.z=f2bf(v.z); o.w=f2bf(v.w);
    int t = i / (NN*32);
    int rem = i - t*(NN*32);
    int r = rem >> 5;
    int f = (rem & 31) * 4;
    *(ushort4*)(outp + (size_t)t*NN*128 + ((size_t)(f>>5)*NN + r)*32 + (f&31)) = o;
  }
}
__global__ void k_bias(const float* bxz, const float* bhz, const float* bxr,
                       const float* bhr, const float* bxh, const float* bhh,
                       float* __restrict__ bz, float* __restrict__ br, float* __restrict__ bh){
  int i = threadIdx.x;  // 384 threads
  int c = i & 127, s = i >> 7;
  if(s==0) bz[c]=bxz[c]+bhz[c];
  else if(s==1) br[c]=bxr[c]+bhr[c];
  else bh[c]=bxh[c]+bhh[c];
}

// ---------- deg (src) histogram via LDS segments -> dinv ----------
__global__ __launch_bounds__(256) void k_hist(const int* __restrict__ ei,
                                              int* __restrict__ part){
  int c = blockIdx.x, seg = blockIdx.y, t = blockIdx.z;
  const int* keys = ei + (size_t)t*2*EE;   // src array
  __shared__ int h[BINSEG];
  for(int i=threadIdx.x;i<BINSEG;i+=256) h[i]=0;
  __syncthreads();
  int base = seg*BINSEG;
  int e0 = c*CHUNK, e1 = e0+CHUNK;
  for(int e=e0+threadIdx.x; e<e1; e+=256){
    int k = keys[e] - base;
    if((unsigned)k < (unsigned)BINSEG) atomicAdd(&h[k],1);
  }
  __syncthreads();
  int* dp = part + ((((size_t)t)*NSEG + seg)*NCH + c)*BINSEG;
  for(int i=threadIdx.x;i<BINSEG;i+=256) dp[i]=h[i];
}
__global__ void k_merge(const int* __restrict__ part, float* __restrict__ dinv4){
  int t = blockIdx.y;
  int n = blockIdx.x*256 + threadIdx.x;
  if(n>=NN) return;
  int seg = n / BINSEG, b = n - seg*BINSEG;
  const int* p = part + ((((size_t)t)*NSEG + seg)*NCH)*BINSEG + b;
  int s = 0;
  #pragma unroll
  for(int c=0;c<NCH;++c) s += p[(size_t)c*BINSEG];
  dinv4[(size_t)t*NN + n] = s>0 ? rsqrtf((float)s) : 0.f;
}

// ---------- coarse bucket counts per (t, chunk) ----------
__global__ __launch_bounds__(256) void k_ccount(const int* __restrict__ ei,
                                                int* __restrict__ ccnt){
  int c = blockIdx.x, t = blockIdx.y;
  const int* dst = ei + (size_t)t*2*EE + EE;
  __shared__ int h[NB2];
  if(threadIdx.x<NB2) h[threadIdx.x]=0;
  __syncthreads();
  int e0 = c*CH2, e1 = e0+CH2;
  for(int e=e0+threadIdx.x; e<e1; e+=256) atomicAdd(&h[dst[e]/CB],1);
  __syncthreads();
  if(threadIdx.x<NB2) ccnt[((size_t)t*NB2 + threadIdx.x)*NCH2 + c] = h[threadIdx.x];
}
__global__ __launch_bounds__(128) void k_cscan(const int* __restrict__ ccnt,
                        int* __restrict__ Abase, int* __restrict__ Bbase,
                        int* __restrict__ tot){
  int t = blockIdx.x, tid = threadIdx.x;
  __shared__ int st[NB2];
  __shared__ int sb[NB2];
  const int* cc = ccnt + (size_t)t*NB2*NCH2;
  if(tid<NB2){
    int s=0;
    for(int c=0;c<NCH2;++c) s += cc[tid*NCH2+c];
    st[tid]=s;
  }
  __syncthreads();
  if(tid==0){
    int run=0;
    for(int b=0;b<NB2;++b){ sb[b]=run; run+=st[b]; }
  }
  __syncthreads();
  if(tid<NB2){
    Bbase[t*NB2+tid]=sb[tid];
    tot[t*NB2+tid]=st[tid];
    int run = sb[tid];
    int* ab = Abase + ((size_t)t*NB2 + tid)*NCH2;
    for(int c=0;c<NCH2;++c){ ab[c]=run; run+=cc[tid*NCH2+c]; }
  }
}
__global__ __launch_bounds__(256) void k_part(const int* __restrict__ ei,
                        const int* __restrict__ Abase, unsigned* __restrict__ staging){
  int c = blockIdx.x, t = blockIdx.y;
  const int* src = ei + (size_t)t*2*EE;
  const int* dst = src + EE;
  unsigned* stg = staging + (size_t)t*EE;
  const int* ab = Abase + (size_t)t*NB2*NCH2;
  __shared__ int h[NB2];
  if(threadIdx.x<NB2) h[threadIdx.x]=0;
  __syncthreads();
  int e0 = c*CH2, e1 = e0+CH2;
  for(int e=e0+threadIdx.x; e<e1; e+=256){
    int s=src[e], d=dst[e];
    int b = d/CB, dl = d - b*CB;
    int r = atomicAdd(&h[b],1);
    stg[ab[b*NCH2 + c] + r] = ((unsigned)dl<<16) | (unsigned)s;
  }
}
// per-bucket LDS counting sort by (dstLocal, src/SEGW) -> meta + offs
__global__ __launch_bounds__(256) void k_sortb(const unsigned* __restrict__ staging,
                        const int* __restrict__ Bbase, const int* __restrict__ tot,
                        const float* __restrict__ dinv4, int2* __restrict__ meta4,
                        int* __restrict__ offs4){
  int b = blockIdx.x, t = blockIdx.y, tid = threadIdx.x;
  __shared__ int cnt[SBINS];
  __shared__ int sums[256];
  __shared__ unsigned sorted[SMAX];
  int sA = Bbase[t*NB2+b];
  int nb = tot[t*NB2+b];
  const unsigned* stg = staging + (size_t)t*EE + sA;
  const float* dinv = dinv4 + (size_t)t*NN;
  int* offs = offs4 + (size_t)t*(NN+1);
  int2* meta = meta4 + (size_t)t*EE + sA;
  for(int i=tid;i<SBINS;i+=256) cnt[i]=0;
  __syncthreads();
  for(int i=tid;i<nb;i+=256){
    unsigned v = stg[i];
    int key = (int)(v>>16)*NSEG2 + (int)(v&0xFFFF)/SEGW;
    atomicAdd(&cnt[key],1);
  }
  __syncthreads();
  int base = tid*SCHUNK;
  int s0 = 0;
  for(int j=0;j<SCHUNK;++j){ int idx=base+j; if(idx<SBINS) s0+=cnt[idx]; }
  sums[tid]=s0; __syncthreads();
  for(int off=1;off<256;off<<=1){
    int v=(tid>=off)?sums[tid-off]:0; __syncthreads();
    sums[tid]+=v; __syncthreads();
  }
  int run = sums[tid]-s0;
  for(int j=0;j<SCHUNK;++j){
    int idx=base+j;
    if(idx<SBINS){ int c=cnt[idx]; cnt[idx]=run; run+=c; }
  }
  __syncthreads();
  for(int dl=tid; dl<CB; dl+=256){
    int n = b*CB + dl;
    if(n<=NN) offs[n] = sA + cnt[dl*NSEG2];
  }
  __syncthreads();
  for(int i=tid;i<nb;i+=256){
    unsigned v = stg[i];
    int key = (int)(v>>16)*NSEG2 + (int)(v&0xFFFF)/SEGW;
    int r = atomicAdd(&cnt[key],1);
    if(r<SMAX) sorted[r]=v;
  }
  __syncthreads();
  for(int i=tid;i<nb;i+=256){
    if(i>=SMAX) break;
    unsigned v = sorted[i];
    int s = v & 0xFFFF, d = b*CB + (v>>16);
    int2 m; m.x = s; m.y = __float_as_int(-dinv[s]*dinv[d]);
    meta[i]=m;
  }
}

// -------- quarter-split single-input gather-SpMM, XCD-pinned quarters --------
// q = (blockIdx&7)>>1: each XCD pair serves one 3.2 MB quarter (fits 4 MB L2).
// 16 groups/block, each 16-lane group owns ONE row, 4-edge unroll gives 4
// independent 64 B gathers in flight per lane (R12 MLP + R13 residency).
// meta via nontemporal load, outputs via nontemporal store.
__global__ __launch_bounds__(256) void k_spmm1q(const int* __restrict__ offs,
                        const int2* __restrict__ meta,
                        const ushort* __restrict__ Xa, ushort* __restrict__ outA){
  int bid = blockIdx.x;
  int q = (bid & 7) >> 1;
  int rank = ((bid >> 3) << 1) | (bid & 1);   // 0..SPB/4-1
  int g = threadIdx.x >> 4;                   // group 0..15
  int l = threadIdx.x & 15;
  const unsigned* XA = (const unsigned*)Xa + (size_t)q*NN*16;
  unsigned* OA = (unsigned*)outA + (size_t)q*NN*16;
  const long long* mp = (const long long*)meta;
  for(int row = rank*16 + g; row < NN; row += (SPB/4)*16){
    int beg = offs[row], end = offs[row+1];
    float ax=0.f, ay=0.f;
    int e = beg;
    for(; e+3<end; e+=4){
      long long m0 = __builtin_nontemporal_load(mp + e+0);
      long long m1 = __builtin_nontemporal_load(mp + e+1);
      long long m2 = __builtin_nontemporal_load(mp + e+2);
      long long m3 = __builtin_nontemporal_load(mp + e+3);
      int s0=(int)(unsigned)(m0&0xffffffffLL), s1=(int)(unsigned)(m1&0xffffffffLL);
      int s2=(int)(unsigned)(m2&0xffffffffLL), s3=(int)(unsigned)(m3&0xffffffffLL);
      float w0=__int_as_float((int)(m0>>32)), w1=__int_as_float((int)(m1>>32));
      float w2=__int_as_float((int)(m2>>32)), w3=__int_as_float((int)(m3>>32));
      unsigned a0=XA[(size_t)s0*16+l], a1=XA[(size_t)s1*16+l];
      unsigned a2=XA[(size_t)s2*16+l], a3=XA[(size_t)s3*16+l];
      ax=fmaf(w0,lo16(a0),ax); ay=fmaf(w0,hi16(a0),ay);
      ax=fmaf(w1,lo16(a1),ax); ay=fmaf(w1,hi16(a1),ay);
      ax=fmaf(w2,lo16(a2),ax); ay=fmaf(w2,hi16(a2),ay);
      ax=fmaf(w3,lo16(a3),ax); ay=fmaf(w3,hi16(a3),ay);
    }
    for(; e<end; ++e){
      long long mv = __builtin_nontemporal_load(mp + e);
      int s = (int)(unsigned)(mv & 0xffffffffLL);
      float w = __int_as_float((int)(mv >> 32));
      unsigned a = XA[(size_t)s*16 + l];
      ax = fmaf(w, lo16(a), ax);
      ay = fmaf(w, hi16(a), ay);
    }
    __builtin_nontemporal_store(packbf(ax, ay), OA + (size_t)row*16 + l);
  }
}

// ---------------- MFMA bf16 GEMM (A operands quarter-major) ----------------
// modes: 0 = fp32 store Cf[r*384+coloff+c]  (GRU main)
//        1 = fp32 beta-accumulate Cf[r*384+coloff+c]  (HR path)
//        2 = bias+relu -> bf16 Cb quarter-major  (decoder 1)
//        3 = bias -> fp32 Cf[r*128+c]       (decoder 2)
__global__ __launch_bounds__(256) void k_mgemm(
    const ushort* __restrict__ A0, const ushort* __restrict__ A1,
    const ushort* __restrict__ A2, const ushort* __restrict__ A3,
    const ushort* __restrict__ A4, const ushort* __restrict__ A5,
    const ushort* __restrict__ Bt, ushort* __restrict__ Cb, float* __restrict__ Cf,
    int K, int ldb, int ngrp, int bnstep, int coloff, int mode, int nwg,
    const float* __restrict__ bias)
{
  __shared__ ushort As[128*64];
  __shared__ ushort Bs[128*64];
  int tid = threadIdx.x;
  int lane = tid & 63;
  int wid = tid >> 6;
  int wr = (wid>>1)*64, wc = (wid&1)*64;
  int bid = blockIdx.x;
  int q = nwg >> 3, r = nwg & 7;
  int xs = bid & 7, j = bid >> 3;
  int logical = xs*q + ((xs<r)?xs:r) + j;
  int bm = logical / ngrp;
  int bn = (logical - bm*ngrp) * bnstep;
  f4_t acc[4][4] = {};
  int srow = tid>>3, sc = tid&7;
  int lr = lane&15, lk = lane>>4;
  int nkt = K>>6;
  for(int kt=0; kt<nkt; ++kt){
    int k0 = kt<<6;
    const ushort* Ac = (k0<128)?A0:(k0<256)?A1:(k0<384)?A2:(k0<512)?A3:(k0<640)?A4:A5;
    int kloc = k0 & 127;
    int f0 = kloc + sc*8;  // 8 contiguous features within one quarter
    size_t aoff = ((size_t)(f0>>5)*NN)*32 + (f0&31);
    #pragma unroll
    for(int p=0;p<4;++p){
      int rr = srow + p*32;
      int gr = bm*128 + rr; if(gr>=NN) gr=NN-1;
      us8 av = *(const us8*)(Ac + aoff + (size_t)gr*32);
      us8 bv = *(const us8*)(Bt + (size_t)(bn*128 + rr)*ldb + k0 + sc*8);
      int wo = (rr*128 + ((sc*16) ^ ((rr&7)<<4))) >> 1;
      *(us8*)(As + wo) = av;
      *(us8*)(Bs + wo) = bv;
    }
    __syncthreads();
    #pragma unroll
    for(int kk=0;kk<2;++kk){
      bf8_t af[4], bfr[4];
      int co = kk*64 + lk*16;
      #pragma unroll
      for(int m=0;m<4;++m){
        int Ra = wr + m*16 + lr;
        af[m]  = *(const bf8_t*)(As + ((Ra*128 + (co ^ ((Ra&7)<<4)))>>1));
        int Rb = wc + m*16 + lr;
        bfr[m] = *(const bf8_t*)(Bs + ((Rb*128 + (co ^ ((Rb&7)<<4)))>>1));
      }
      #pragma unroll
      for(int m=0;m<4;++m)
        #pragma unroll
        for(int n=0;n<4;++n)
          acc[m][n] = __builtin_amdgcn_mfma_f32_16x16x32_bf16(af[m], bfr[n], acc[m][n], 0,0,0);
    }
    __syncthreads();
  }
  int row0 = bm*128 + wr + lk*4;
  int col0 = bn*128 + wc + lr;
  #pragma unroll
  for(int m=0;m<4;++m){
    #pragma unroll
    for(int i=0;i<4;++i){
      int rI = row0 + m*16 + i;
      if(rI<NN){
        if(mode<=1){
          float* cp = Cf + (size_t)rI*384 + coloff + col0;
          #pragma unroll
          for(int n=0;n<4;++n){
            float v = acc[m][n][i];
            if(mode==1) v += cp[n*16];
            cp[n*16] = v;
          }
        } else if(mode==2){
          #pragma unroll
          for(int n=0;n<4;++n){
            int c = col0 + n*16;
            float v = acc[m][n][i] + bias[c];
            Cb[((size_t)(c>>5)*NN + rI)*32 + (c&31)] = f2bf(fmaxf(v,0.f));
          }
        } else {
          #pragma unroll
          for(int n=0;n<4;++n){
            int c = col0 + n*16;
            Cf[(size_t)rI*128 + c] = acc[m][n][i] + bias[c];
          }
        }
      }
    }
  }
}

// Z = sigmoid(OX[:,0:128]+bz); HRb(qm) = bf16(H * sigmoid(OX[:,128:256]+br))
__global__ void k_combA(const float* __restrict__ OX, const float* __restrict__ H,
                        const float* __restrict__ bz, const float* __restrict__ br,
                        float* __restrict__ Z, ushort* __restrict__ HRb){
  int i = blockIdx.x*256 + threadIdx.x;
  if(i>=NN*FF) return;
  int r = i>>7, c = i&127;
  float zv = sigm(OX[r*384+c]     + bz[c]);
  float rv = sigm(OX[r*384+128+c] + br[c]);
  float hr = H[i]*rv;
  Z[i]=zv;
  HRb[((size_t)(c>>5)*NN + r)*32 + (c&31)] = f2bf(hr);
}
// Htilde = tanh(OX[:,256:384]+bh); Hnew = Z*H + (1-Z)*Htilde; Hnb quarter-major
__global__ void k_combB(const float* __restrict__ OX, const float* __restrict__ Z,
                        const float* __restrict__ H, const float* __restrict__ bh,
                        float* __restrict__ Hn, ushort* __restrict__ Hnb,
                        float* __restrict__ Hout2){
  int i = blockIdx.x*256 + threadIdx.x;
  if(i>=NN*FF) return;
  int r = i>>7, c = i&127;
  float ht = tanhf(OX[r*384+256+c] + bh[c]);
  float z = Z[i];
  float hn = z*H[i] + (1.f-z)*ht;
  Hn[i] = hn;
  Hnb[((size_t)(c>>5)*NN + r)*32 + (c&31)] = f2bf(hn);
  if(Hout2) Hout2[i] = hn;
}
// t=0 (H==0): Hn = (1 - sigm(OXz+bz)) * tanh(OXh+bh)
__global__ void k_gru0(const float* __restrict__ OX, const float* __restrict__ bz,
                       const float* __restrict__ bh, float* __restrict__ Hn,
                       ushort* __restrict__ Hnb){
  int i = blockIdx.x*256 + threadIdx.x;
  if(i>=NN*FF) return;
  int r = i>>7, c = i&127;
  float z  = sigm(OX[r*384+c] + bz[c]);
  float ht = tanhf(OX[r*384+256+c] + bh[c]);
  float hn = (1.f - z)*ht;
  Hn[i]=hn;
  Hnb[((size_t)(c>>5)*NN + r)*32 + (c&31)] = f2bf(hn);
}

// pack x-side weights, REBASED: chunks [X:(W0-W2), U1:W1, U2:2*W2]
__global__ void k_packx(const float* __restrict__ Wxz, const float* __restrict__ Wxr,
                        const float* __restrict__ Wxh, const float* __restrict__ Whz,
                        const float* __restrict__ Whr, ushort* __restrict__ Bt){
  int i = blockIdx.x*256 + threadIdx.x;
  if(i>=384*768) return;
  int c = i/768, k = i - c*768;
  int g = c>>7, j = c&127;
  int kb = k>>7, kk = k&127;
  float v;
  int e = kk*128 + j;
  if(kb<3){
    const float* W = (g==0)?Wxz:((g==1)?Wxr:Wxh);
    v = (kb==0) ? (W[e] - W[2*16384 + e]) : (kb==1 ? W[16384 + e] : 2.f*W[2*16384 + e]);
  } else if(g<2){
    const float* W = (g==0)?Whz:Whr;
    int kb2 = kb-3;
    v = (kb2==0) ? (W[e] - W[2*16384 + e]) : (kb2==1 ? W[16384 + e] : 2.f*W[2*16384 + e]);
  } else v = 0.f;
  Bt[i] = f2bf(v);
}
__global__ void k_packh(const float* __restrict__ Whh, ushort* __restrict__ Bt){
  int i = blockIdx.x*256 + threadIdx.x;
  if(i>=128*384) return;
  int c = i/384, k = i - c*384;
  int kb = k>>7, kk = k&127;
  int e = kk*128 + c;
  float v = (kb==0) ? (Whh[e] - Whh[2*16384 + e]) : (kb==1 ? Whh[16384 + e] : 2.f*Whh[2*16384 + e]);
  Bt[i] = f2bf(v);
}
// decoder weight: Bt[c][k] = W[k][c], 128x128
__global__ void k_packd(const float* __restrict__ W, ushort* __restrict__ Bt){
  int i = blockIdx.x*256 + threadIdx.x;
  if(i>=128*128) return;
  int c = i>>7, k = i&127;
  Bt[i] = f2bf(W[k*128 + c]);
}

extern "C" void kernel_launch(void* const* d_in, const int* in_sizes, int n_in,
                              void* d_out, int out_size, void* d_ws, size_t ws_size,
                              hipStream_t stream) {
  const float* x   = (const float*)d_in[0];
  const int*   ei  = (const int*)d_in[1];
  const float* Wxz = (const float*)d_in[2];
  const float* Whz = (const float*)d_in[3];
  const float* Wxr = (const float*)d_in[4];
  const float* Whr = (const float*)d_in[5];
  const float* Wxh = (const float*)d_in[6];
  const float* Whh = (const float*)d_in[7];
  const float* bxz = (const float*)d_in[8];
  const float* bhz = (const float*)d_in[9];
  const float* bxr = (const float*)d_in[10];
  const float* bhr = (const float*)d_in[11];
  const float* bxh = (const float*)d_in[12];
  const float* bhh = (const float*)d_in[13];
  const float* Wd1 = (const float*)d_in[14];
  const float* bd1 = (const float*)d_in[15];
  const float* Wd2 = (const float*)d_in[16];
  const float* bd2 = (const float*)d_in[17];
  float* out = (float*)d_out;

  char* p = (char*)d_ws;
  auto alloc = [&](size_t bytes)->void*{ void* r = (void*)p; p += (bytes+255)&~(size_t)255; return r; };
  const size_t NFB  = (size_t)NN*FF*4;
  const size_t NFB2 = (size_t)NN*FF*2;
  float* Ha   = (float*)alloc(NFB);
  float* Hb   = (float*)alloc(NFB);
  float* OX   = (float*)alloc((size_t)NN*384*4);
  float* Zb   = (float*)alloc(NFB);
  ushort* xtb4= (ushort*)alloc(NFB2*TT);
  ushort* A1b = (ushort*)alloc(NFB2);
  ushort* A2b = (ushort*)alloc(NFB2);
  ushort* A3b = (ushort*)alloc(NFB2);
  ushort* A4b = (ushort*)alloc(NFB2);
  ushort* HRb = (ushort*)alloc(NFB2);
  ushort* Hab = (ushort*)alloc(NFB2);
  ushort* Hbb = (ushort*)alloc(NFB2);
  ushort* Btx = (ushort*)alloc((size_t)384*768*2);
  ushort* Bth = (ushort*)alloc((size_t)128*384*2);
  ushort* Btd1= (ushort*)alloc((size_t)128*128*2);
  ushort* Btd2= (ushort*)alloc((size_t)128*128*2);
  float* bzc  = (float*)alloc(128*4);
  float* brc  = (float*)alloc(128*4);
  float* bhc  = (float*)alloc(128*4);
  float* dinv4= (float*)alloc((size_t)TT*NN*4);
  int* ccnt   = (int*)alloc((size_t)TT*NB2*NCH2*4);
  int* Abase  = (int*)alloc((size_t)TT*NB2*NCH2*4);
  int* Bbase  = (int*)alloc((size_t)TT*NB2*4);
  int* tot    = (int*)alloc((size_t)TT*NB2*4);
  int* offs4  = (int*)alloc((size_t)TT*(NN+1)*4);
  int2* meta4 = (int2*)alloc((size_t)TT*EE*8);
  // aliases consumed before GRU loop: deg partials in Ha (25.6MB), staging in Hb (12.8MB)
  int* partial = (int*)Ha;
  unsigned* staging = (unsigned*)Hb;

  const int fb = (NN*FF+255)/256;
  const int MT = (NN+127)/128;      // 391

  // ---- one-time prep ----
  k_packx<<<(384*768+255)/256,256,0,stream>>>(Wxz,Wxr,Wxh,Whz,Whr,Btx);
  k_packh<<<(128*384+255)/256,256,0,stream>>>(Whh,Bth);
  k_packd<<<64,256,0,stream>>>(Wd1,Btd1);
  k_packd<<<64,256,0,stream>>>(Wd2,Btd2);
  k_bias<<<1,384,0,stream>>>(bxz,bhz,bxr,bhr,bxh,bhh,bzc,brc,bhc);
  k_cast4<<<(TT*NN*FF/4+255)/256,256,0,stream>>>(x, xtb4, TT*NN*FF/4);
  dim3 gh(NCH, NSEG, TT);
  k_hist<<<gh,256,0,stream>>>(ei, partial);
  dim3 gm((NN+255)/256, TT);
  k_merge<<<gm,256,0,stream>>>(partial, dinv4);
  dim3 gc(NCH2, TT);
  k_ccount<<<gc,256,0,stream>>>(ei, ccnt);
  k_cscan<<<TT,128,0,stream>>>(ccnt, Abase, Bbase, tot);
  k_part<<<gc,256,0,stream>>>(ei, Abase, staging);
  dim3 gs(NB2, TT);
  k_sortb<<<gs,256,0,stream>>>(staging, Bbase, tot, dinv4, meta4, offs4);

  float* Hc = Ha; float* Hn = Hb;
  ushort* Hcb = Hab; ushort* Hnb = Hbb;
  for(int t=0;t<TT;++t){
    const ushort* xtb = xtb4 + (size_t)t*NN*FF;
    const int* offs = offs4 + (size_t)t*(NN+1);
    const int2* meta = meta4 + (size_t)t*EE;
    if(t==0){
      k_spmm1q<<<SPB,256,0,stream>>>(offs,meta, xtb, A1b);
      k_spmm1q<<<SPB,256,0,stream>>>(offs,meta, A1b, A2b);
      int nwg0 = MT*2;
      k_mgemm<<<nwg0,256,0,stream>>>(xtb,A1b,A2b,nullptr,nullptr,nullptr,
          Btx, nullptr, OX, 384, 768, 2, 2, 0, 0, nwg0, nullptr);
      k_gru0<<<fb,256,0,stream>>>(OX, bzc, bhc, Hn, Hnb);
    } else {
      k_spmm1q<<<SPB,256,0,stream>>>(offs,meta, xtb, A1b);
      k_spmm1q<<<SPB,256,0,stream>>>(offs,meta, Hcb, A3b);
      k_spmm1q<<<SPB,256,0,stream>>>(offs,meta, A1b, A2b);
      k_spmm1q<<<SPB,256,0,stream>>>(offs,meta, A3b, A4b);
      int nwg1 = MT*3;
      k_mgemm<<<nwg1,256,0,stream>>>(xtb,A1b,A2b,Hcb,A3b,A4b,
          Btx, nullptr, OX, 768, 768, 3, 1, 0, 0, nwg1, nullptr);
      k_combA<<<fb,256,0,stream>>>(OX,Hc,bzc,brc,Zb,HRb);
      k_spmm1q<<<SPB,256,0,stream>>>(offs,meta, HRb, A3b);
      k_spmm1q<<<SPB,256,0,stream>>>(offs,meta, A3b, A4b);
      int nwg3 = MT;
      k_mgemm<<<nwg3,256,0,stream>>>(HRb,A3b,A4b,nullptr,nullptr,nullptr,
          Bth, nullptr, OX, 384, 384, 1, 1, 256, 1, nwg3, nullptr);
      float* hout2 = (t==TT-1) ? (out + (size_t)NN*FF) : nullptr;
      k_combB<<<fb,256,0,stream>>>(OX,Zb,Hc,bhc,Hn,Hnb,hout2);
    }
    float* tmp=Hc; Hc=Hn; Hn=tmp;
    ushort* tb=Hcb; Hcb=Hnb; Hnb=tb;
  }
  // decoder: relu(H@Wd1+bd1)@Wd2+bd2  (MFMA bf16; A1b as quarter-major temp)
  k_mgemm<<<MT,256,0,stream>>>(Hcb,nullptr,nullptr,nullptr,nullptr,nullptr,
      Btd1, A1b, nullptr, 128, 128, 1, 1, 0, 2, MT, bd1);
  k_mgemm<<<MT,256,0,stream>>>(A1b,nullptr,nullptr,nullptr,nullptr,nullptr,
      Btd2, nullptr, out, 128, 128, 1, 1, 0, 3, MT, bd2);
}

// Round 15
// 1382.032 us; speedup vs baseline: 2.0143x; 1.3159x over previous
//
#include <hip/hip_runtime.h>
#include <math.h>

#define NN 50000
#define TT 4
#define FF 128
#define EE 800000
#define NSEG 4      // node-space segments for LDS deg histogram
#define BINSEG 12500
#define NCH 32      // edge chunks for deg histogram
#define CHUNK 25000
#define NCH2 128    // edge chunks for partition
#define CH2 6250    // EE/NCH2
#define NB2 64      // coarse dst buckets
#define CB 782      // nodes per bucket (64*782=50048 >= NN)
#define NSEG2 16    // src segments for within-row quantile sort
#define SEGW 3125   // 50000/16
#define SBINS (CB*NSEG2)   // 12512
#define SCHUNK 49          // ceil(SBINS/256)
#define SMAX 13312  // LDS sort capacity per bucket (mean 12512, +7 sigma; 52 KB)

typedef __attribute__((ext_vector_type(8))) short bf8_t;
typedef __attribute__((ext_vector_type(4))) float f4_t;
typedef __attribute__((ext_vector_type(8))) ushort us8;

__device__ inline ushort f2bf(float f){
  union { float f; unsigned u; } v; v.f = f;
  unsigned u = v.u;
  unsigned r = (u + 0x7fff + ((u>>16)&1)) >> 16;  // RNE
  return (ushort)r;
}
__device__ inline float lo16(unsigned u){ union{unsigned u;float f;}v; v.u=u<<16; return v.f; }
__device__ inline float hi16(unsigned u){ union{unsigned u;float f;}v; v.u=u&0xffff0000u; return v.f; }
__device__ inline unsigned packbf(float x, float y){
  return (unsigned)f2bf(x) | ((unsigned)f2bf(y)<<16);
}
__device__ inline float sigm(float x){ return 1.f/(1.f+expf(-x)); }

// ---------------- utility ----------------
__global__ void k_cast4(const float* __restrict__ in, ushort* __restrict__ outp, int n4){
  int i = blockIdx.x*256 + threadIdx.x;
  if(i<n4){
    float4 v = ((const float4*)in)[i];
    ushort4 o; o.x=f2bf(v.x); o.y=f2bf(v.y); o.z=f2bf(v.z); o.w=f2bf(v.w);
    ((ushort4*)outp)[i]=o;
  }
}
__global__ void k_bias(const float* bxz, const float* bhz, const float* bxr,
                       const float* bhr, const float* bxh, const float* bhh,
                       float* __restrict__ bz, float* __restrict__ br, float* __restrict__ bh){
  int i = threadIdx.x;  // 384 threads
  int c = i & 127, s = i >> 7;
  if(s==0) bz[c]=bxz[c]+bhz[c];
  else if(s==1) br[c]=bxr[c]+bhr[c];
  else bh[c]=bxh[c]+bhh[c];
}

// ---------- deg (src) histogram via LDS segments -> dinv ----------
__global__ __launch_bounds__(256) void k_hist(const int* __restrict__ ei,
                                              int* __restrict__ part){
  int c = blockIdx.x, seg = blockIdx.y, t = blockIdx.z;
  const int* keys = ei + (size_t)t*2*EE;   // src array
  __shared__ int h[BINSEG];
  for(int i=threadIdx.x;i<BINSEG;i+=256) h[i]=0;
  __syncthreads();
  int base = seg*BINSEG;
  int e0 = c*CHUNK, e1 = e0+CHUNK;
  for(int e=e0+threadIdx.x; e<e1; e+=256){
    int k = keys[e] - base;
    if((unsigned)k < (unsigned)BINSEG) atomicAdd(&h[k],1);
  }
  __syncthreads();
  int* dp = part + ((((size_t)t)*NSEG + seg)*NCH + c)*BINSEG;
  for(int i=threadIdx.x;i<BINSEG;i+=256) dp[i]=h[i];
}
__global__ void k_merge(const int* __restrict__ part, float* __restrict__ dinv4){
  int t = blockIdx.y;
  int n = blockIdx.x*256 + threadIdx.x;
  if(n>=NN) return;
  int seg = n / BINSEG, b = n - seg*BINSEG;
  const int* p = part + ((((size_t)t)*NSEG + seg)*NCH)*BINSEG + b;
  int s = 0;
  #pragma unroll
  for(int c=0;c<NCH;++c) s += p[(size_t)c*BINSEG];
  dinv4[(size_t)t*NN + n] = s>0 ? rsqrtf((float)s) : 0.f;
}

// ---------- coarse bucket counts per (t, chunk) ----------
__global__ __launch_bounds__(256) void k_ccount(const int* __restrict__ ei,
                                                int* __restrict__ ccnt){
  int c = blockIdx.x, t = blockIdx.y;
  const int* dst = ei + (size_t)t*2*EE + EE;
  __shared__ int h[NB2];
  if(threadIdx.x<NB2) h[threadIdx.x]=0;
  __syncthreads();
  int e0 = c*CH2, e1 = e0+CH2;
  for(int e=e0+threadIdx.x; e<e1; e+=256) atomicAdd(&h[dst[e]/CB],1);
  __syncthreads();
  if(threadIdx.x<NB2) ccnt[((size_t)t*NB2 + threadIdx.x)*NCH2 + c] = h[threadIdx.x];
}
__global__ __launch_bounds__(128) void k_cscan(const int* __restrict__ ccnt,
                        int* __restrict__ Abase, int* __restrict__ Bbase,
                        int* __restrict__ tot){
  int t = blockIdx.x, tid = threadIdx.x;
  __shared__ int st[NB2];
  __shared__ int sb[NB2];
  const int* cc = ccnt + (size_t)t*NB2*NCH2;
  if(tid<NB2){
    int s=0;
    for(int c=0;c<NCH2;++c) s += cc[tid*NCH2+c];
    st[tid]=s;
  }
  __syncthreads();
  if(tid==0){
    int run=0;
    for(int b=0;b<NB2;++b){ sb[b]=run; run+=st[b]; }
  }
  __syncthreads();
  if(tid<NB2){
    Bbase[t*NB2+tid]=sb[tid];
    tot[t*NB2+tid]=st[tid];
    int run = sb[tid];
    int* ab = Abase + ((size_t)t*NB2 + tid)*NCH2;
    for(int c=0;c<NCH2;++c){ ab[c]=run; run+=cc[tid*NCH2+c]; }
  }
}
__global__ __launch_bounds__(256) void k_part(const int* __restrict__ ei,
                        const int* __restrict__ Abase, unsigned* __restrict__ staging){
  int c = blockIdx.x, t = blockIdx.y;
  const int* src = ei + (size_t)t*2*EE;
  const int* dst = src + EE;
  unsigned* stg = staging + (size_t)t*EE;
  const int* ab = Abase + (size_t)t*NB2*NCH2;
  __shared__ int h[NB2];
  if(threadIdx.x<NB2) h[threadIdx.x]=0;
  __syncthreads();
  int e0 = c*CH2, e1 = e0+CH2;
  for(int e=e0+threadIdx.x; e<e1; e+=256){
    int s=src[e], d=dst[e];
    int b = d/CB, dl = d - b*CB;
    int r = atomicAdd(&h[b],1);
    stg[ab[b*NCH2 + c] + r] = ((unsigned)dl<<16) | (unsigned)s;
  }
}
// per-bucket LDS counting sort by (dstLocal, src/SEGW) -> meta + offs
// rank-scatter through LDS sorted[]; meta written coalesced
__global__ __launch_bounds__(256) void k_sortb(const unsigned* __restrict__ staging,
                        const int* __restrict__ Bbase, const int* __restrict__ tot,
                        const float* __restrict__ dinv4, int2* __restrict__ meta4,
                        int* __restrict__ offs4){
  int b = blockIdx.x, t = blockIdx.y, tid = threadIdx.x;
  __shared__ int cnt[SBINS];
  __shared__ int sums[256];
  __shared__ unsigned sorted[SMAX];
  int sA = Bbase[t*NB2+b];
  int nb = tot[t*NB2+b];
  const unsigned* stg = staging + (size_t)t*EE + sA;
  const float* dinv = dinv4 + (size_t)t*NN;
  int* offs = offs4 + (size_t)t*(NN+1);
  int2* meta = meta4 + (size_t)t*EE + sA;
  for(int i=tid;i<SBINS;i+=256) cnt[i]=0;
  __syncthreads();
  for(int i=tid;i<nb;i+=256){
    unsigned v = stg[i];
    int key = (int)(v>>16)*NSEG2 + (int)(v&0xFFFF)/SEGW;
    atomicAdd(&cnt[key],1);
  }
  __syncthreads();
  int base = tid*SCHUNK;
  int s0 = 0;
  for(int j=0;j<SCHUNK;++j){ int idx=base+j; if(idx<SBINS) s0+=cnt[idx]; }
  sums[tid]=s0; __syncthreads();
  for(int off=1;off<256;off<<=1){
    int v=(tid>=off)?sums[tid-off]:0; __syncthreads();
    sums[tid]+=v; __syncthreads();
  }
  int run = sums[tid]-s0;
  for(int j=0;j<SCHUNK;++j){
    int idx=base+j;
    if(idx<SBINS){ int c=cnt[idx]; cnt[idx]=run; run+=c; }
  }
  __syncthreads();
  for(int dl=tid; dl<CB; dl+=256){
    int n = b*CB + dl;
    if(n<=NN) offs[n] = sA + cnt[dl*NSEG2];
  }
  __syncthreads();
  for(int i=tid;i<nb;i+=256){
    unsigned v = stg[i];
    int key = (int)(v>>16)*NSEG2 + (int)(v&0xFFFF)/SEGW;
    int r = atomicAdd(&cnt[key],1);
    if(r<SMAX) sorted[r]=v;
  }
  __syncthreads();
  for(int i=tid;i<nb;i+=256){
    if(i>=SMAX) break;
    unsigned v = sorted[i];
    int s = v & 0xFFFF, d = b*CB + (v>>16);
    int2 m; m.x = s; m.y = __float_as_int(-dinv[s]*dinv[d]);
    meta[i]=m;
  }
}

// -------- fused dual-input bf16 gather-SpMM (row-major; 8-edge unroll, NT streams) --------
__global__ void k_spmm2(const int* __restrict__ offs, const int2* __restrict__ meta,
                        const ushort* __restrict__ Xa, const ushort* __restrict__ Xb,
                        ushort* __restrict__ outA, ushort* __restrict__ outB){
  int wid = threadIdx.x>>6, lane = threadIdx.x&63;
  int row = blockIdx.x*4+wid;
  if(row>=NN) return;
  int beg = offs[row], end = offs[row+1];
  const unsigned* XA = (const unsigned*)Xa;
  const unsigned* XB = (const unsigned*)Xb;
  const long long* mp = (const long long*)meta;
  float ax=0.f, ay=0.f, bx=0.f, by=0.f;
  int e = beg;
  for(; e+7<end; e+=8){
    long long m0=__builtin_nontemporal_load(mp+e+0), m1=__builtin_nontemporal_load(mp+e+1);
    long long m2=__builtin_nontemporal_load(mp+e+2), m3=__builtin_nontemporal_load(mp+e+3);
    long long m4=__builtin_nontemporal_load(mp+e+4), m5=__builtin_nontemporal_load(mp+e+5);
    long long m6=__builtin_nontemporal_load(mp+e+6), m7=__builtin_nontemporal_load(mp+e+7);
    int s0=(int)(unsigned)m0, s1=(int)(unsigned)m1, s2=(int)(unsigned)m2, s3=(int)(unsigned)m3;
    int s4=(int)(unsigned)m4, s5=(int)(unsigned)m5, s6=(int)(unsigned)m6, s7=(int)(unsigned)m7;
    float w0=__int_as_float((int)(m0>>32)), w1=__int_as_float((int)(m1>>32));
    float w2=__int_as_float((int)(m2>>32)), w3=__int_as_float((int)(m3>>32));
    float w4=__int_as_float((int)(m4>>32)), w5=__int_as_float((int)(m5>>32));
    float w6=__int_as_float((int)(m6>>32)), w7=__int_as_float((int)(m7>>32));
    unsigned a0=XA[(size_t)s0*64+lane], a1=XA[(size_t)s1*64+lane];
    unsigned a2=XA[(size_t)s2*64+lane], a3=XA[(size_t)s3*64+lane];
    unsigned a4=XA[(size_t)s4*64+lane], a5=XA[(size_t)s5*64+lane];
    unsigned a6=XA[(size_t)s6*64+lane], a7=XA[(size_t)s7*64+lane];
    unsigned b0=XB[(size_t)s0*64+lane], b1=XB[(size_t)s1*64+lane];
    unsigned b2=XB[(size_t)s2*64+lane], b3=XB[(size_t)s3*64+lane];
    unsigned b4=XB[(size_t)s4*64+lane], b5=XB[(size_t)s5*64+lane];
    unsigned b6=XB[(size_t)s6*64+lane], b7=XB[(size_t)s7*64+lane];
    ax=fmaf(w0,lo16(a0),ax); ay=fmaf(w0,hi16(a0),ay);
    ax=fmaf(w1,lo16(a1),ax); ay=fmaf(w1,hi16(a1),ay);
    ax=fmaf(w2,lo16(a2),ax); ay=fmaf(w2,hi16(a2),ay);
    ax=fmaf(w3,lo16(a3),ax); ay=fmaf(w3,hi16(a3),ay);
    ax=fmaf(w4,lo16(a4),ax); ay=fmaf(w4,hi16(a4),ay);
    ax=fmaf(w5,lo16(a5),ax); ay=fmaf(w5,hi16(a5),ay);
    ax=fmaf(w6,lo16(a6),ax); ay=fmaf(w6,hi16(a6),ay);
    ax=fmaf(w7,lo16(a7),ax); ay=fmaf(w7,hi16(a7),ay);
    bx=fmaf(w0,lo16(b0),bx); by=fmaf(w0,hi16(b0),by);
    bx=fmaf(w1,lo16(b1),bx); by=fmaf(w1,hi16(b1),by);
    bx=fmaf(w2,lo16(b2),bx); by=fmaf(w2,hi16(b2),by);
    bx=fmaf(w3,lo16(b3),bx); by=fmaf(w3,hi16(b3),by);
    bx=fmaf(w4,lo16(b4),bx); by=fmaf(w4,hi16(b4),by);
    bx=fmaf(w5,lo16(b5),bx); by=fmaf(w5,hi16(b5),by);
    bx=fmaf(w6,lo16(b6),bx); by=fmaf(w6,hi16(b6),by);
    bx=fmaf(w7,lo16(b7),bx); by=fmaf(w7,hi16(b7),by);
  }
  for(; e<end; ++e){
    long long mv = __builtin_nontemporal_load(mp+e);
    int s=(int)(unsigned)mv; float w=__int_as_float((int)(mv>>32));
    unsigned a=XA[(size_t)s*64+lane], b=XB[(size_t)s*64+lane];
    ax=fmaf(w,lo16(a),ax); ay=fmaf(w,hi16(a),ay);
    bx=fmaf(w,lo16(b),bx); by=fmaf(w,hi16(b),by);
  }
  int oi = row*64+lane;
  __builtin_nontemporal_store(packbf(ax, ay), (unsigned*)outA + oi);
  __builtin_nontemporal_store(packbf(bx, by), (unsigned*)outB + oi);
}
__global__ void k_spmm1(const int* __restrict__ offs, const int2* __restrict__ meta,
                        const ushort* __restrict__ Xa, ushort* __restrict__ outA){
  int wid = threadIdx.x>>6, lane = threadIdx.x&63;
  int row = blockIdx.x*4+wid;
  if(row>=NN) return;
  int beg = offs[row], end = offs[row+1];
  const unsigned* XA = (const unsigned*)Xa;
  const long long* mp = (const long long*)meta;
  float ax=0.f, ay=0.f;
  int e = beg;
  for(; e+7<end; e+=8){
    long long m0=__builtin_nontemporal_load(mp+e+0), m1=__builtin_nontemporal_load(mp+e+1);
    long long m2=__builtin_nontemporal_load(mp+e+2), m3=__builtin_nontemporal_load(mp+e+3);
    long long m4=__builtin_nontemporal_load(mp+e+4), m5=__builtin_nontemporal_load(mp+e+5);
    long long m6=__builtin_nontemporal_load(mp+e+6), m7=__builtin_nontemporal_load(mp+e+7);
    int s0=(int)(unsigned)m0, s1=(int)(unsigned)m1, s2=(int)(unsigned)m2, s3=(int)(unsigned)m3;
    int s4=(int)(unsigned)m4, s5=(int)(unsigned)m5, s6=(int)(unsigned)m6, s7=(int)(unsigned)m7;
    float w0=__int_as_float((int)(m0>>32)), w1=__int_as_float((int)(m1>>32));
    float w2=__int_as_float((int)(m2>>32)), w3=__int_as_float((int)(m3>>32));
    float w4=__int_as_float((int)(m4>>32)), w5=__int_as_float((int)(m5>>32));
    float w6=__int_as_float((int)(m6>>32)), w7=__int_as_float((int)(m7>>32));
    unsigned a0=XA[(size_t)s0*64+lane], a1=XA[(size_t)s1*64+lane];
    unsigned a2=XA[(size_t)s2*64+lane], a3=XA[(size_t)s3*64+lane];
    unsigned a4=XA[(size_t)s4*64+lane], a5=XA[(size_t)s5*64+lane];
    unsigned a6=XA[(size_t)s6*64+lane], a7=XA[(size_t)s7*64+lane];
    ax=fmaf(w0,lo16(a0),ax); ay=fmaf(w0,hi16(a0),ay);
    ax=fmaf(w1,lo16(a1),ax); ay=fmaf(w1,hi16(a1),ay);
    ax=fmaf(w2,lo16(a2),ax); ay=fmaf(w2,hi16(a2),ay);
    ax=fmaf(w3,lo16(a3),ax); ay=fmaf(w3,hi16(a3),ay);
    ax=fmaf(w4,lo16(a4),ax); ay=fmaf(w4,hi16(a4),ay);
    ax=fmaf(w5,lo16(a5),ax); ay=fmaf(w5,hi16(a5),ay);
    ax=fmaf(w6,lo16(a6),ax); ay=fmaf(w6,hi16(a6),ay);
    ax=fmaf(w7,lo16(a7),ax); ay=fmaf(w7,hi16(a7),ay);
  }
  for(; e<end; ++e){
    long long mv = __builtin_nontemporal_load(mp+e);
    int s=(int)(unsigned)mv; float w=__int_as_float((int)(mv>>32));
    unsigned a=XA[(size_t)s*64+lane];
    ax=fmaf(w,lo16(a),ax); ay=fmaf(w,hi16(a),ay);
  }
  __builtin_nontemporal_store(packbf(ax, ay), (unsigned*)outA + row*64 + lane);
}

// ---------------- MFMA bf16 GEMM ----------------
// modes: 0 = fp32 store Cf[r*384+coloff+c]  (GRU main)
//        1 = fp32 beta-accumulate Cf[r*384+coloff+c]  (HR path)
//        2 = bias+relu -> bf16 Cb[r*128+c]  (decoder 1)
//        3 = bias -> fp32 Cf[r*128+c]       (decoder 2)
__global__ __launch_bounds__(256) void k_mgemm(
    const ushort* __restrict__ A0, const ushort* __restrict__ A1,
    const ushort* __restrict__ A2, const ushort* __restrict__ A3,
    const ushort* __restrict__ A4, const ushort* __restrict__ A5,
    const ushort* __restrict__ Bt, ushort* __restrict__ Cb, float* __restrict__ Cf,
    int K, int ldb, int ngrp, int bnstep, int coloff, int mode, int nwg,
    const float* __restrict__ bias)
{
  __shared__ ushort As[128*64];
  __shared__ ushort Bs[128*64];
  int tid = threadIdx.x;
  int lane = tid & 63;
  int wid = tid >> 6;
  int wr = (wid>>1)*64, wc = (wid&1)*64;
  int bid = blockIdx.x;
  int q = nwg >> 3, r = nwg & 7;
  int xs = bid & 7, j = bid >> 3;
  int logical = xs*q + ((xs<r)?xs:r) + j;
  int bm = logical / ngrp;
  int bn = (logical - bm*ngrp) * bnstep;
  f4_t acc[4][4] = {};
  int srow = tid>>3, sc = tid&7;
  int lr = lane&15, lk = lane>>4;
  int nkt = K>>6;
  for(int kt=0; kt<nkt; ++kt){
    int k0 = kt<<6;
    const ushort* Ac = (k0<128)?A0:(k0<256)?A1:(k0<384)?A2:(k0<512)?A3:(k0<640)?A4:A5;
    int kloc = k0 & 127;
    #pragma unroll
    for(int p=0;p<4;++p){
      int rr = srow + p*32;
      int gr = bm*128 + rr; if(gr>=NN) gr=NN-1;
      us8 av = *(const us8*)(Ac + (size_t)gr*128 + kloc + sc*8);
      us8 bv = *(const us8*)(Bt + (size_t)(bn*128 + rr)*ldb + k0 + sc*8);
      int wo = (rr*128 + ((sc*16) ^ ((rr&7)<<4))) >> 1;
      *(us8*)(As + wo) = av;
      *(us8*)(Bs + wo) = bv;
    }
    __syncthreads();
    #pragma unroll
    for(int kk=0;kk<2;++kk){
      bf8_t af[4], bfr[4];
      int co = kk*64 + lk*16;
      #pragma unroll
      for(int m=0;m<4;++m){
        int Ra = wr + m*16 + lr;
        af[m]  = *(const bf8_t*)(As + ((Ra*128 + (co ^ ((Ra&7)<<4)))>>1));
        int Rb = wc + m*16 + lr;
        bfr[m] = *(const bf8_t*)(Bs + ((Rb*128 + (co ^ ((Rb&7)<<4)))>>1));
      }
      #pragma unroll
      for(int m=0;m<4;++m)
        #pragma unroll
        for(int n=0;n<4;++n)
          acc[m][n] = __builtin_amdgcn_mfma_f32_16x16x32_bf16(af[m], bfr[n], acc[m][n], 0,0,0);
    }
    __syncthreads();
  }
  int row0 = bm*128 + wr + lk*4;
  int col0 = bn*128 + wc + lr;
  #pragma unroll
  for(int m=0;m<4;++m){
    #pragma unroll
    for(int i=0;i<4;++i){
      int rI = row0 + m*16 + i;
      if(rI<NN){
        if(mode<=1){
          float* cp = Cf + (size_t)rI*384 + coloff + col0;
          #pragma unroll
          for(int n=0;n<4;++n){
            float v = acc[m][n][i];
            if(mode==1) v += cp[n*16];
            cp[n*16] = v;
          }
        } else if(mode==2){
          #pragma unroll
          for(int n=0;n<4;++n){
            int c = col0 + n*16;
            float v = acc[m][n][i] + bias[c];
            Cb[(size_t)rI*128 + c] = f2bf(fmaxf(v,0.f));
          }
        } else {
          #pragma unroll
          for(int n=0;n<4;++n){
            int c = col0 + n*16;
            Cf[(size_t)rI*128 + c] = acc[m][n][i] + bias[c];
          }
        }
      }
    }
  }
}

// Z = sigmoid(OX[:,0:128]+bz); HRb = bf16(H * sigmoid(OX[:,128:256]+br))
__global__ void k_combA(const float* __restrict__ OX, const float* __restrict__ H,
                        const float* __restrict__ bz, const float* __restrict__ br,
                        float* __restrict__ Z, ushort* __restrict__ HRb){
  int i = blockIdx.x*256 + threadIdx.x;
  if(i>=NN*FF) return;
  int r = i>>7, c = i&127;
  float zv = sigm(OX[r*384+c]     + bz[c]);
  float rv = sigm(OX[r*384+128+c] + br[c]);
  float hr = H[i]*rv;
  Z[i]=zv; HRb[i]=f2bf(hr);
}
// Htilde = tanh(OX[:,256:384]+bh); Hnew = Z*H + (1-Z)*Htilde
__global__ void k_combB(const float* __restrict__ OX, const float* __restrict__ Z,
                        const float* __restrict__ H, const float* __restrict__ bh,
                        float* __restrict__ Hn, ushort* __restrict__ Hnb,
                        float* __restrict__ Hout2){
  int i = blockIdx.x*256 + threadIdx.x;
  if(i>=NN*FF) return;
  int r = i>>7, c = i&127;
  float ht = tanhf(OX[r*384+256+c] + bh[c]);
  float z = Z[i];
  float hn = z*H[i] + (1.f-z)*ht;
  Hn[i] = hn; Hnb[i] = f2bf(hn);
  if(Hout2) Hout2[i] = hn;
}
// t=0 (H==0): Hn = (1 - sigm(OXz+bz)) * tanh(OXh+bh)
__global__ void k_gru0(const float* __restrict__ OX, const float* __restrict__ bz,
                       const float* __restrict__ bh, float* __restrict__ Hn,
                       ushort* __restrict__ Hnb){
  int i = blockIdx.x*256 + threadIdx.x;
  if(i>=NN*FF) return;
  int r = i>>7, c = i&127;
  float z  = sigm(OX[r*384+c] + bz[c]);
  float ht = tanhf(OX[r*384+256+c] + bh[c]);
  float hn = (1.f - z)*ht;
  Hn[i]=hn; Hnb[i]=f2bf(hn);
}

// pack x-side weights, REBASED: chunks [X:(W0-W2), U1:W1, U2:2*W2]
__global__ void k_packx(const float* __restrict__ Wxz, const float* __restrict__ Wxr,
                        const float* __restrict__ Wxh, const float* __restrict__ Whz,
                        const float* __restrict__ Whr, ushort* __restrict__ Bt){
  int i = blockIdx.x*256 + threadIdx.x;
  if(i>=384*768) return;
  int c = i/768, k = i - c*768;
  int g = c>>7, j = c&127;
  int kb = k>>7, kk = k&127;
  float v;
  int e = kk*128 + j;
  if(kb<3){
    const float* W = (g==0)?Wxz:((g==1)?Wxr:Wxh);
    v = (kb==0) ? (W[e] - W[2*16384 + e]) : (kb==1 ? W[16384 + e] : 2.f*W[2*16384 + e]);
  } else if(g<2){
    const float* W = (g==0)?Whz:Whr;
    int kb2 = kb-3;
    v = (kb2==0) ? (W[e] - W[2*16384 + e]) : (kb2==1 ? W[16384 + e] : 2.f*W[2*16384 + e]);
  } else v = 0.f;
  Bt[i] = f2bf(v);
}
__global__ void k_packh(const float* __restrict__ Whh, ushort* __restrict__ Bt){
  int i = blockIdx.x*256 + threadIdx.x;
  if(i>=128*384) return;
  int c = i/384, k = i - c*384;
  int kb = k>>7, kk = k&127;
  int e = kk*128 + c;
  float v = (kb==0) ? (Whh[e] - Whh[2*16384 + e]) : (kb==1 ? Whh[16384 + e] : 2.f*Whh[2*16384 + e]);
  Bt[i] = f2bf(v);
}
// decoder weight: Bt[c][k] = W[k][c], 128x128
__global__ void k_packd(const float* __restrict__ W, ushort* __restrict__ Bt){
  int i = blockIdx.x*256 + threadIdx.x;
  if(i>=128*128) return;
  int c = i>>7, k = i&127;
  Bt[i] = f2bf(W[k*128 + c]);
}

extern "C" void kernel_launch(void* const* d_in, const int* in_sizes, int n_in,
                              void* d_out, int out_size, void* d_ws, size_t ws_size,
                              hipStream_t stream) {
  const float* x   = (const float*)d_in[0];
  const int*   ei  = (const int*)d_in[1];
  const float* Wxz = (const float*)d_in[2];
  const float* Whz = (const float*)d_in[3];
  const float* Wxr = (const float*)d_in[4];
  const float* Whr = (const float*)d_in[5];
  const float* Wxh = (const float*)d_in[6];
  const float* Whh = (const float*)d_in[7];
  const float* bxz = (const float*)d_in[8];
  const float* bhz = (const float*)d_in[9];
  const float* bxr = (const float*)d_in[10];
  const float* bhr = (const float*)d_in[11];
  const float* bxh = (const float*)d_in[12];
  const float* bhh = (const float*)d_in[13];
  const float* Wd1 = (const float*)d_in[14];
  const float* bd1 = (const float*)d_in[15];
  const float* Wd2 = (const float*)d_in[16];
  const float* bd2 = (const float*)d_in[17];
  float* out = (float*)d_out;

  char* p = (char*)d_ws;
  auto alloc = [&](size_t bytes)->void*{ void* r = (void*)p; p += (bytes+255)&~(size_t)255; return r; };
  const size_t NFB  = (size_t)NN*FF*4;
  const size_t NFB2 = (size_t)NN*FF*2;
  float* Ha   = (float*)alloc(NFB);
  float* Hb   = (float*)alloc(NFB);
  float* OX   = (float*)alloc((size_t)NN*384*4);
  float* Zb   = (float*)alloc(NFB);
  ushort* xtb4= (ushort*)alloc(NFB2*TT);
  ushort* A1b = (ushort*)alloc(NFB2);
  ushort* A2b = (ushort*)alloc(NFB2);
  ushort* A3b = (ushort*)alloc(NFB2);
  ushort* A4b = (ushort*)alloc(NFB2);
  ushort* HRb = (ushort*)alloc(NFB2);
  ushort* Hab = (ushort*)alloc(NFB2);
  ushort* Hbb = (ushort*)alloc(NFB2);
  ushort* Btx = (ushort*)alloc((size_t)384*768*2);
  ushort* Bth = (ushort*)alloc((size_t)128*384*2);
  ushort* Btd1= (ushort*)alloc((size_t)128*128*2);
  ushort* Btd2= (ushort*)alloc((size_t)128*128*2);
  float* bzc  = (float*)alloc(128*4);
  float* brc  = (float*)alloc(128*4);
  float* bhc  = (float*)alloc(128*4);
  float* dinv4= (float*)alloc((size_t)TT*NN*4);
  int* ccnt   = (int*)alloc((size_t)TT*NB2*NCH2*4);
  int* Abase  = (int*)alloc((size_t)TT*NB2*NCH2*4);
  int* Bbase  = (int*)alloc((size_t)TT*NB2*4);
  int* tot    = (int*)alloc((size_t)TT*NB2*4);
  int* offs4  = (int*)alloc((size_t)TT*(NN+1)*4);
  int2* meta4 = (int2*)alloc((size_t)TT*EE*8);
  // aliases consumed before GRU loop: deg partials in Ha (25.6MB), staging in Hb (12.8MB)
  int* partial = (int*)Ha;
  unsigned* staging = (unsigned*)Hb;

  const int fb = (NN*FF+255)/256;
  const int sg = (NN+3)/4;
  const int MT = (NN+127)/128;      // 391

  // ---- one-time prep ----
  k_packx<<<(384*768+255)/256,256,0,stream>>>(Wxz,Wxr,Wxh,Whz,Whr,Btx);
  k_packh<<<(128*384+255)/256,256,0,stream>>>(Whh,Bth);
  k_packd<<<64,256,0,stream>>>(Wd1,Btd1);
  k_packd<<<64,256,0,stream>>>(Wd2,Btd2);
  k_bias<<<1,384,0,stream>>>(bxz,bhz,bxr,bhr,bxh,bhh,bzc,brc,bhc);
  k_cast4<<<(TT*NN*FF/4+255)/256,256,0,stream>>>(x, xtb4, TT*NN*FF/4);
  dim3 gh(NCH, NSEG, TT);
  k_hist<<<gh,256,0,stream>>>(ei, partial);
  dim3 gm((NN+255)/256, TT);
  k_merge<<<gm,256,0,stream>>>(partial, dinv4);
  dim3 gc(NCH2, TT);
  k_ccount<<<gc,256,0,stream>>>(ei, ccnt);
  k_cscan<<<TT,128,0,stream>>>(ccnt, Abase, Bbase, tot);
  k_part<<<gc,256,0,stream>>>(ei, Abase, staging);
  dim3 gs(NB2, TT);
  k_sortb<<<gs,256,0,stream>>>(staging, Bbase, tot, dinv4, meta4, offs4);

  float* Hc = Ha; float* Hn = Hb;
  ushort* Hcb = Hab; ushort* Hnb = Hbb;
  for(int t=0;t<TT;++t){
    const ushort* xtb = xtb4 + (size_t)t*NN*FF;
    const int* offs = offs4 + (size_t)t*(NN+1);
    const int2* meta = meta4 + (size_t)t*EE;
    if(t==0){
      k_spmm1<<<sg,256,0,stream>>>(offs,meta, xtb, A1b);
      k_spmm1<<<sg,256,0,stream>>>(offs,meta, A1b, A2b);
      int nwg0 = MT*2;
      k_mgemm<<<nwg0,256,0,stream>>>(xtb,A1b,A2b,nullptr,nullptr,nullptr,
          Btx, nullptr, OX, 384, 768, 2, 2, 0, 0, nwg0, nullptr);
      k_gru0<<<fb,256,0,stream>>>(OX, bzc, bhc, Hn, Hnb);
    } else {
      k_spmm2<<<sg,256,0,stream>>>(offs,meta, xtb,Hcb, A1b,A3b);
      k_spmm2<<<sg,256,0,stream>>>(offs,meta, A1b,A3b, A2b,A4b);
      int nwg1 = MT*3;
      k_mgemm<<<nwg1,256,0,stream>>>(xtb,A1b,A2b,Hcb,A3b,A4b,
          Btx, nullptr, OX, 768, 768, 3, 1, 0, 0, nwg1, nullptr);
      k_combA<<<fb,256,0,stream>>>(OX,Hc,bzc,brc,Zb,HRb);
      k_spmm1<<<sg,256,0,stream>>>(offs,meta, HRb, A3b);
      k_spmm1<<<sg,256,0,stream>>>(offs,meta, A3b, A4b);
      int nwg3 = MT;
      k_mgemm<<<nwg3,256,0,stream>>>(HRb,A3b,A4b,nullptr,nullptr,nullptr,
          Bth, nullptr, OX, 384, 384, 1, 1, 256, 1, nwg3, nullptr);
      float* hout2 = (t==TT-1) ? (out + (size_t)NN*FF) : nullptr;
      k_combB<<<fb,256,0,stream>>>(OX,Zb,Hc,bhc,Hn,Hnb,hout2);
    }
    float* tmp=Hc; Hc=Hn; Hn=tmp;
    ushort* tb=Hcb; Hcb=Hnb; Hnb=tb;
  }
  // decoder: relu(H@Wd1+bd1)@Wd2+bd2  (MFMA bf16; A1b as bf16 temp)
  k_mgemm<<<MT,256,0,stream>>>(Hcb,nullptr,nullptr,nullptr,nullptr,nullptr,
      Btd1, A1b, nullptr, 128, 128, 1, 1, 0, 2, MT, bd1);
  k_mgemm<<<MT,256,0,stream>>>(A1b,nullptr,nullptr,nullptr,nullptr,nullptr,
      Btd2, nullptr, out, 128, 128, 1, 1, 0, 3, MT, bd2);
}

// Round 16
// 1250.058 us; speedup vs baseline: 2.2269x; 1.1056x over previous
//
#include <hip/hip_runtime.h>
#include <math.h>

#define NN 50000
#define TT 4
#define FF 128
#define EE 800000
#define NSEG 4      // node-space segments for LDS deg histogram
#define BINSEG 12500
#define NCH 32      // edge chunks for deg histogram
#define CHUNK 25000
#define NCH2 128    // edge chunks for partition
#define CH2 6250    // EE/NCH2
#define NB2 64      // coarse dst buckets
#define CB 782      // nodes per bucket (64*782=50048 >= NN)
#define NSEG2 16    // src segments for within-row quantile sort
#define SEGW 3125   // 50000/16
#define SBINS (CB*NSEG2)   // 12512
#define SCHUNK 49          // ceil(SBINS/256)
#define SMAX 13312  // LDS sort capacity per bucket (mean 12512, +7 sigma; 52 KB)

typedef __attribute__((ext_vector_type(8))) short bf8_t;
typedef __attribute__((ext_vector_type(4))) float f4_t;
typedef __attribute__((ext_vector_type(8))) ushort us8;

__device__ inline ushort f2bf(float f){
  union { float f; unsigned u; } v; v.f = f;
  unsigned u = v.u;
  unsigned r = (u + 0x7fff + ((u>>16)&1)) >> 16;  // RNE
  return (ushort)r;
}
__device__ inline float lo16(unsigned u){ union{unsigned u;float f;}v; v.u=u<<16; return v.f; }
__device__ inline float hi16(unsigned u){ union{unsigned u;float f;}v; v.u=u&0xffff0000u; return v.f; }
__device__ inline unsigned packbf(float x, float y){
  return (unsigned)f2bf(x) | ((unsigned)f2bf(y)<<16);
}
__device__ inline float sigm(float x){ return 1.f/(1.f+expf(-x)); }

// ---------------- utility ----------------
__global__ void k_cast4(const float* __restrict__ in, ushort* __restrict__ outp, int n4){
  int i = blockIdx.x*256 + threadIdx.x;
  if(i<n4){
    float4 v = ((const float4*)in)[i];
    ushort4 o; o.x=f2bf(v.x); o.y=f2bf(v.y); o.z=f2bf(v.z); o.w=f2bf(v.w);
    ((ushort4*)outp)[i]=o;
  }
}
__global__ void k_bias(const float* bxz, const float* bhz, const float* bxr,
                       const float* bhr, const float* bxh, const float* bhh,
                       float* __restrict__ bz, float* __restrict__ br, float* __restrict__ bh){
  int i = threadIdx.x;  // 384 threads
  int c = i & 127, s = i >> 7;
  if(s==0) bz[c]=bxz[c]+bhz[c];
  else if(s==1) br[c]=bxr[c]+bhr[c];
  else bh[c]=bxh[c]+bhh[c];
}

// ---------- deg (src) histogram via LDS segments -> dinv ----------
__global__ __launch_bounds__(256) void k_hist(const int* __restrict__ ei,
                                              int* __restrict__ part){
  int c = blockIdx.x, seg = blockIdx.y, t = blockIdx.z;
  const int* keys = ei + (size_t)t*2*EE;   // src array
  __shared__ int h[BINSEG];
  for(int i=threadIdx.x;i<BINSEG;i+=256) h[i]=0;
  __syncthreads();
  int base = seg*BINSEG;
  int e0 = c*CHUNK, e1 = e0+CHUNK;
  for(int e=e0+threadIdx.x; e<e1; e+=256){
    int k = keys[e] - base;
    if((unsigned)k < (unsigned)BINSEG) atomicAdd(&h[k],1);
  }
  __syncthreads();
  int* dp = part + ((((size_t)t)*NSEG + seg)*NCH + c)*BINSEG;
  for(int i=threadIdx.x;i<BINSEG;i+=256) dp[i]=h[i];
}
__global__ void k_merge(const int* __restrict__ part, float* __restrict__ dinv4){
  int t = blockIdx.y;
  int n = blockIdx.x*256 + threadIdx.x;
  if(n>=NN) return;
  int seg = n / BINSEG, b = n - seg*BINSEG;
  const int* p = part + ((((size_t)t)*NSEG + seg)*NCH)*BINSEG + b;
  int s = 0;
  #pragma unroll
  for(int c=0;c<NCH;++c) s += p[(size_t)c*BINSEG];
  dinv4[(size_t)t*NN + n] = s>0 ? rsqrtf((float)s) : 0.f;
}

// ---------- coarse bucket counts per (t, chunk) ----------
__global__ __launch_bounds__(256) void k_ccount(const int* __restrict__ ei,
                                                int* __restrict__ ccnt){
  int c = blockIdx.x, t = blockIdx.y;
  const int* dst = ei + (size_t)t*2*EE + EE;
  __shared__ int h[NB2];
  if(threadIdx.x<NB2) h[threadIdx.x]=0;
  __syncthreads();
  int e0 = c*CH2, e1 = e0+CH2;
  for(int e=e0+threadIdx.x; e<e1; e+=256) atomicAdd(&h[dst[e]/CB],1);
  __syncthreads();
  if(threadIdx.x<NB2) ccnt[((size_t)t*NB2 + threadIdx.x)*NCH2 + c] = h[threadIdx.x];
}
__global__ __launch_bounds__(128) void k_cscan(const int* __restrict__ ccnt,
                        int* __restrict__ Abase, int* __restrict__ Bbase,
                        int* __restrict__ tot){
  int t = blockIdx.x, tid = threadIdx.x;
  __shared__ int st[NB2];
  __shared__ int sb[NB2];
  const int* cc = ccnt + (size_t)t*NB2*NCH2;
  if(tid<NB2){
    int s=0;
    for(int c=0;c<NCH2;++c) s += cc[tid*NCH2+c];
    st[tid]=s;
  }
  __syncthreads();
  if(tid==0){
    int run=0;
    for(int b=0;b<NB2;++b){ sb[b]=run; run+=st[b]; }
  }
  __syncthreads();
  if(tid<NB2){
    Bbase[t*NB2+tid]=sb[tid];
    tot[t*NB2+tid]=st[tid];
    int run = sb[tid];
    int* ab = Abase + ((size_t)t*NB2 + tid)*NCH2;
    for(int c=0;c<NCH2;++c){ ab[c]=run; run+=cc[tid*NCH2+c]; }
  }
}
__global__ __launch_bounds__(256) void k_part(const int* __restrict__ ei,
                        const int* __restrict__ Abase, unsigned* __restrict__ staging){
  int c = blockIdx.x, t = blockIdx.y;
  const int* src = ei + (size_t)t*2*EE;
  const int* dst = src + EE;
  unsigned* stg = staging + (size_t)t*EE;
  const int* ab = Abase + (size_t)t*NB2*NCH2;
  __shared__ int h[NB2];
  if(threadIdx.x<NB2) h[threadIdx.x]=0;
  __syncthreads();
  int e0 = c*CH2, e1 = e0+CH2;
  for(int e=e0+threadIdx.x; e<e1; e+=256){
    int s=src[e], d=dst[e];
    int b = d/CB, dl = d - b*CB;
    int r = atomicAdd(&h[b],1);
    stg[ab[b*NCH2 + c] + r] = ((unsigned)dl<<16) | (unsigned)s;
  }
}
// per-bucket LDS counting sort by (dstLocal, src/SEGW) -> meta + offs
__global__ __launch_bounds__(256) void k_sortb(const unsigned* __restrict__ staging,
                        const int* __restrict__ Bbase, const int* __restrict__ tot,
                        const float* __restrict__ dinv4, int2* __restrict__ meta4,
                        int* __restrict__ offs4){
  int b = blockIdx.x, t = blockIdx.y, tid = threadIdx.x;
  __shared__ int cnt[SBINS];
  __shared__ int sums[256];
  __shared__ unsigned sorted[SMAX];
  int sA = Bbase[t*NB2+b];
  int nb = tot[t*NB2+b];
  const unsigned* stg = staging + (size_t)t*EE + sA;
  const float* dinv = dinv4 + (size_t)t*NN;
  int* offs = offs4 + (size_t)t*(NN+1);
  int2* meta = meta4 + (size_t)t*EE + sA;
  for(int i=tid;i<SBINS;i+=256) cnt[i]=0;
  __syncthreads();
  for(int i=tid;i<nb;i+=256){
    unsigned v = stg[i];
    int key = (int)(v>>16)*NSEG2 + (int)(v&0xFFFF)/SEGW;
    atomicAdd(&cnt[key],1);
  }
  __syncthreads();
  int base = tid*SCHUNK;
  int s0 = 0;
  for(int j=0;j<SCHUNK;++j){ int idx=base+j; if(idx<SBINS) s0+=cnt[idx]; }
  sums[tid]=s0; __syncthreads();
  for(int off=1;off<256;off<<=1){
    int v=(tid>=off)?sums[tid-off]:0; __syncthreads();
    sums[tid]+=v; __syncthreads();
  }
  int run = sums[tid]-s0;
  for(int j=0;j<SCHUNK;++j){
    int idx=base+j;
    if(idx<SBINS){ int c=cnt[idx]; cnt[idx]=run; run+=c; }
  }
  __syncthreads();
  for(int dl=tid; dl<CB; dl+=256){
    int n = b*CB + dl;
    if(n<=NN) offs[n] = sA + cnt[dl*NSEG2];
  }
  __syncthreads();
  for(int i=tid;i<nb;i+=256){
    unsigned v = stg[i];
    int key = (int)(v>>16)*NSEG2 + (int)(v&0xFFFF)/SEGW;
    int r = atomicAdd(&cnt[key],1);
    if(r<SMAX) sorted[r]=v;
  }
  __syncthreads();
  for(int i=tid;i<nb;i+=256){
    if(i>=SMAX) break;
    unsigned v = sorted[i];
    int s = v & 0xFFFF, d = b*CB + (v>>16);
    int2 m; m.x = s; m.y = __float_as_int(-dinv[s]*dinv[d]);
    meta[i]=m;
  }
}

// -------- fused dual-input bf16 gather-SpMM (R11 exact: 4-edge unroll, plain ld/st) --------
__global__ void k_spmm2(const int* __restrict__ offs, const int2* __restrict__ meta,
                        const ushort* __restrict__ Xa, const ushort* __restrict__ Xb,
                        ushort* __restrict__ outA, ushort* __restrict__ outB){
  int wid = threadIdx.x>>6, lane = threadIdx.x&63;
  int row = blockIdx.x*4+wid;
  if(row>=NN) return;
  int beg = offs[row], end = offs[row+1];
  const unsigned* XA = (const unsigned*)Xa;
  const unsigned* XB = (const unsigned*)Xb;
  float ax=0.f, ay=0.f, bx=0.f, by=0.f;
  int e = beg;
  for(; e+3<end; e+=4){
    int2 p0=meta[e+0], p1=meta[e+1], p2=meta[e+2], p3=meta[e+3];
    float w0=__int_as_float(p0.y), w1=__int_as_float(p1.y);
    float w2=__int_as_float(p2.y), w3=__int_as_float(p3.y);
    unsigned a0=XA[p0.x*64+lane], a1=XA[p1.x*64+lane], a2=XA[p2.x*64+lane], a3=XA[p3.x*64+lane];
    unsigned b0=XB[p0.x*64+lane], b1=XB[p1.x*64+lane], b2=XB[p2.x*64+lane], b3=XB[p3.x*64+lane];
    ax=fmaf(w0,lo16(a0),ax); ay=fmaf(w0,hi16(a0),ay);
    ax=fmaf(w1,lo16(a1),ax); ay=fmaf(w1,hi16(a1),ay);
    ax=fmaf(w2,lo16(a2),ax); ay=fmaf(w2,hi16(a2),ay);
    ax=fmaf(w3,lo16(a3),ax); ay=fmaf(w3,hi16(a3),ay);
    bx=fmaf(w0,lo16(b0),bx); by=fmaf(w0,hi16(b0),by);
    bx=fmaf(w1,lo16(b1),bx); by=fmaf(w1,hi16(b1),by);
    bx=fmaf(w2,lo16(b2),bx); by=fmaf(w2,hi16(b2),by);
    bx=fmaf(w3,lo16(b3),bx); by=fmaf(w3,hi16(b3),by);
  }
  for(; e<end; ++e){
    int2 pm=meta[e]; float w=__int_as_float(pm.y);
    unsigned a=XA[pm.x*64+lane], b=XB[pm.x*64+lane];
    ax=fmaf(w,lo16(a),ax); ay=fmaf(w,hi16(a),ay);
    bx=fmaf(w,lo16(b),bx); by=fmaf(w,hi16(b),by);
  }
  int oi = row*64+lane;
  ((unsigned*)outA)[oi] = packbf(ax, ay);
  ((unsigned*)outB)[oi] = packbf(bx, by);
}
__global__ void k_spmm1(const int* __restrict__ offs, const int2* __restrict__ meta,
                        const ushort* __restrict__ Xa, ushort* __restrict__ outA){
  int wid = threadIdx.x>>6, lane = threadIdx.x&63;
  int row = blockIdx.x*4+wid;
  if(row>=NN) return;
  int beg = offs[row], end = offs[row+1];
  const unsigned* XA = (const unsigned*)Xa;
  float ax=0.f, ay=0.f;
  int e = beg;
  for(; e+3<end; e+=4){
    int2 p0=meta[e+0], p1=meta[e+1], p2=meta[e+2], p3=meta[e+3];
    float w0=__int_as_float(p0.y), w1=__int_as_float(p1.y);
    float w2=__int_as_float(p2.y), w3=__int_as_float(p3.y);
    unsigned a0=XA[p0.x*64+lane], a1=XA[p1.x*64+lane], a2=XA[p2.x*64+lane], a3=XA[p3.x*64+lane];
    ax=fmaf(w0,lo16(a0),ax); ay=fmaf(w0,hi16(a0),ay);
    ax=fmaf(w1,lo16(a1),ax); ay=fmaf(w1,hi16(a1),ay);
    ax=fmaf(w2,lo16(a2),ax); ay=fmaf(w2,hi16(a2),ay);
    ax=fmaf(w3,lo16(a3),ax); ay=fmaf(w3,hi16(a3),ay);
  }
  for(; e<end; ++e){
    int2 pm=meta[e]; float w=__int_as_float(pm.y);
    unsigned a=XA[pm.x*64+lane];
    ax=fmaf(w,lo16(a),ax); ay=fmaf(w,hi16(a),ay);
  }
  ((unsigned*)outA)[row*64+lane] = packbf(ax, ay);
}

// ---------------- MFMA bf16 GEMM ----------------
// modes: 0 = fp32 store Cf[r*384+coloff+c]  (GRU main)
//        1 = fp32 beta-accumulate Cf[r*384+coloff+c]  (HR path)
//        2 = bias+relu -> bf16 Cb[r*128+c]  (decoder 1)
//        3 = bias -> fp32 Cf[r*128+c]       (decoder 2)
__global__ __launch_bounds__(256) void k_mgemm(
    const ushort* __restrict__ A0, const ushort* __restrict__ A1,
    const ushort* __restrict__ A2, const ushort* __restrict__ A3,
    const ushort* __restrict__ A4, const ushort* __restrict__ A5,
    const ushort* __restrict__ Bt, ushort* __restrict__ Cb, float* __restrict__ Cf,
    int K, int ldb, int ngrp, int bnstep, int coloff, int mode, int nwg,
    const float* __restrict__ bias)
{
  __shared__ ushort As[128*64];
  __shared__ ushort Bs[128*64];
  int tid = threadIdx.x;
  int lane = tid & 63;
  int wid = tid >> 6;
  int wr = (wid>>1)*64, wc = (wid&1)*64;
  int bid = blockIdx.x;
  int q = nwg >> 3, r = nwg & 7;
  int xs = bid & 7, j = bid >> 3;
  int logical = xs*q + ((xs<r)?xs:r) + j;
  int bm = logical / ngrp;
  int bn = (logical - bm*ngrp) * bnstep;
  f4_t acc[4][4] = {};
  int srow = tid>>3, sc = tid&7;
  int lr = lane&15, lk = lane>>4;
  int nkt = K>>6;
  for(int kt=0; kt<nkt; ++kt){
    int k0 = kt<<6;
    const ushort* Ac = (k0<128)?A0:(k0<256)?A1:(k0<384)?A2:(k0<512)?A3:(k0<640)?A4:A5;
    int kloc = k0 & 127;
    #pragma unroll
    for(int p=0;p<4;++p){
      int rr = srow + p*32;
      int gr = bm*128 + rr; if(gr>=NN) gr=NN-1;
      us8 av = *(const us8*)(Ac + (size_t)gr*128 + kloc + sc*8);
      us8 bv = *(const us8*)(Bt + (size_t)(bn*128 + rr)*ldb + k0 + sc*8);
      int wo = (rr*128 + ((sc*16) ^ ((rr&7)<<4))) >> 1;
      *(us8*)(As + wo) = av;
      *(us8*)(Bs + wo) = bv;
    }
    __syncthreads();
    #pragma unroll
    for(int kk=0;kk<2;++kk){
      bf8_t af[4], bfr[4];
      int co = kk*64 + lk*16;
      #pragma unroll
      for(int m=0;m<4;++m){
        int Ra = wr + m*16 + lr;
        af[m]  = *(const bf8_t*)(As + ((Ra*128 + (co ^ ((Ra&7)<<4)))>>1));
        int Rb = wc + m*16 + lr;
        bfr[m] = *(const bf8_t*)(Bs + ((Rb*128 + (co ^ ((Rb&7)<<4)))>>1));
      }
      #pragma unroll
      for(int m=0;m<4;++m)
        #pragma unroll
        for(int n=0;n<4;++n)
          acc[m][n] = __builtin_amdgcn_mfma_f32_16x16x32_bf16(af[m], bfr[n], acc[m][n], 0,0,0);
    }
    __syncthreads();
  }
  int row0 = bm*128 + wr + lk*4;
  int col0 = bn*128 + wc + lr;
  #pragma unroll
  for(int m=0;m<4;++m){
    #pragma unroll
    for(int i=0;i<4;++i){
      int rI = row0 + m*16 + i;
      if(rI<NN){
        if(mode<=1){
          float* cp = Cf + (size_t)rI*384 + coloff + col0;
          #pragma unroll
          for(int n=0;n<4;++n){
            float v = acc[m][n][i];
            if(mode==1) v += cp[n*16];
            cp[n*16] = v;
          }
        } else if(mode==2){
          #pragma unroll
          for(int n=0;n<4;++n){
            int c = col0 + n*16;
            float v = acc[m][n][i] + bias[c];
            Cb[(size_t)rI*128 + c] = f2bf(fmaxf(v,0.f));
          }
        } else {
          #pragma unroll
          for(int n=0;n<4;++n){
            int c = col0 + n*16;
            Cf[(size_t)rI*128 + c] = acc[m][n][i] + bias[c];
          }
        }
      }
    }
  }
}

// Z = sigmoid(OX[:,0:128]+bz); HRb = bf16(H * sigmoid(OX[:,128:256]+br))   (2 elems/thread)
__global__ void k_combA(const float* __restrict__ OX, const float* __restrict__ H,
                        const float* __restrict__ bz, const float* __restrict__ br,
                        float* __restrict__ Z, ushort* __restrict__ HRb){
  int i = blockIdx.x*256 + threadIdx.x;
  if(i>=NN*64) return;
  int r = i>>6, c2 = (i&63)*2;
  float2 zv2 = *(const float2*)(OX + (size_t)r*384 + c2);
  float2 rv2 = *(const float2*)(OX + (size_t)r*384 + 128 + c2);
  float2 h   = ((const float2*)H)[i];
  float z0 = sigm(zv2.x + bz[c2]),   z1 = sigm(zv2.y + bz[c2+1]);
  float r0 = sigm(rv2.x + br[c2]),   r1 = sigm(rv2.y + br[c2+1]);
  float2 zz; zz.x=z0; zz.y=z1;
  ((float2*)Z)[i] = zz;
  ((unsigned*)HRb)[i] = packbf(h.x*r0, h.y*r1);
}
// Htilde = tanh(OX[:,256:384]+bh); Hnew = Z*H + (1-Z)*Htilde   (2 elems/thread)
__global__ void k_combB(const float* __restrict__ OX, const float* __restrict__ Z,
                        const float* __restrict__ H, const float* __restrict__ bh,
                        float* __restrict__ Hn, ushort* __restrict__ Hnb,
                        float* __restrict__ Hout2){
  int i = blockIdx.x*256 + threadIdx.x;
  if(i>=NN*64) return;
  int r = i>>6, c2 = (i&63)*2;
  float2 hv = *(const float2*)(OX + (size_t)r*384 + 256 + c2);
  float2 z  = ((const float2*)Z)[i];
  float2 h  = ((const float2*)H)[i];
  float t0 = tanhf(hv.x + bh[c2]);
  float t1 = tanhf(hv.y + bh[c2+1]);
  float hn0 = z.x*h.x + (1.f-z.x)*t0;
  float hn1 = z.y*h.y + (1.f-z.y)*t1;
  float2 hn; hn.x=hn0; hn.y=hn1;
  ((float2*)Hn)[i] = hn;
  ((unsigned*)Hnb)[i] = packbf(hn0, hn1);
  if(Hout2) ((float2*)Hout2)[i] = hn;
}
// t=0 (H==0): Hn = (1 - sigm(OXz+bz)) * tanh(OXh+bh)   (2 elems/thread)
__global__ void k_gru0(const float* __restrict__ OX, const float* __restrict__ bz,
                       const float* __restrict__ bh, float* __restrict__ Hn,
                       ushort* __restrict__ Hnb){
  int i = blockIdx.x*256 + threadIdx.x;
  if(i>=NN*64) return;
  int r = i>>6, c2 = (i&63)*2;
  float2 zv = *(const float2*)(OX + (size_t)r*384 + c2);
  float2 hv = *(const float2*)(OX + (size_t)r*384 + 256 + c2);
  float z0 = sigm(zv.x + bz[c2]), z1 = sigm(zv.y + bz[c2+1]);
  float t0 = tanhf(hv.x + bh[c2]);
  float t1 = tanhf(hv.y + bh[c2+1]);
  float hn0 = (1.f-z0)*t0, hn1 = (1.f-z1)*t1;
  float2 hn; hn.x=hn0; hn.y=hn1;
  ((float2*)Hn)[i] = hn;
  ((unsigned*)Hnb)[i] = packbf(hn0, hn1);
}

// pack x-side weights, REBASED: chunks [X:(W0-W2), U1:W1, U2:2*W2]
__global__ void k_packx(const float* __restrict__ Wxz, const float* __restrict__ Wxr,
                        const float* __restrict__ Wxh, const float* __restrict__ Whz,
                        const float* __restrict__ Whr, ushort* __restrict__ Bt){
  int i = blockIdx.x*256 + threadIdx.x;
  if(i>=384*768) return;
  int c = i/768, k = i - c*768;
  int g = c>>7, j = c&127;
  int kb = k>>7, kk = k&127;
  float v;
  int e = kk*128 + j;
  if(kb<3){
    const float* W = (g==0)?Wxz:((g==1)?Wxr:Wxh);
    v = (kb==0) ? (W[e] - W[2*16384 + e]) : (kb==1 ? W[16384 + e] : 2.f*W[2*16384 + e]);
  } else if(g<2){
    const float* W = (g==0)?Whz:Whr;
    int kb2 = kb-3;
    v = (kb2==0) ? (W[e] - W[2*16384 + e]) : (kb2==1 ? W[16384 + e] : 2.f*W[2*16384 + e]);
  } else v = 0.f;
  Bt[i] = f2bf(v);
}
__global__ void k_packh(const float* __restrict__ Whh, ushort* __restrict__ Bt){
  int i = blockIdx.x*256 + threadIdx.x;
  if(i>=128*384) return;
  int c = i/384, k = i - c*384;
  int kb = k>>7, kk = k&127;
  int e = kk*128 + c;
  float v = (kb==0) ? (Whh[e] - Whh[2*16384 + e]) : (kb==1 ? Whh[16384 + e] : 2.f*Whh[2*16384 + e]);
  Bt[i] = f2bf(v);
}
// decoder weight: Bt[c][k] = W[k][c], 128x128
__global__ void k_packd(const float* __restrict__ W, ushort* __restrict__ Bt){
  int i = blockIdx.x*256 + threadIdx.x;
  if(i>=128*128) return;
  int c = i>>7, k = i&127;
  Bt[i] = f2bf(W[k*128 + c]);
}

extern "C" void kernel_launch(void* const* d_in, const int* in_sizes, int n_in,
                              void* d_out, int out_size, void* d_ws, size_t ws_size,
                              hipStream_t stream) {
  const float* x   = (const float*)d_in[0];
  const int*   ei  = (const int*)d_in[1];
  const float* Wxz = (const float*)d_in[2];
  const float* Whz = (const float*)d_in[3];
  const float* Wxr = (const float*)d_in[4];
  const float* Whr = (const float*)d_in[5];
  const float* Wxh = (const float*)d_in[6];
  const float* Whh = (const float*)d_in[7];
  const float* bxz = (const float*)d_in[8];
  const float* bhz = (const float*)d_in[9];
  const float* bxr = (const float*)d_in[10];
  const float* bhr = (const float*)d_in[11];
  const float* bxh = (const float*)d_in[12];
  const float* bhh = (const float*)d_in[13];
  const float* Wd1 = (const float*)d_in[14];
  const float* bd1 = (const float*)d_in[15];
  const float* Wd2 = (const float*)d_in[16];
  const float* bd2 = (const float*)d_in[17];
  float* out = (float*)d_out;

  char* p = (char*)d_ws;
  auto alloc = [&](size_t bytes)->void*{ void* r = (void*)p; p += (bytes+255)&~(size_t)255; return r; };
  const size_t NFB  = (size_t)NN*FF*4;
  const size_t NFB2 = (size_t)NN*FF*2;
  float* Ha   = (float*)alloc(NFB);
  float* Hb   = (float*)alloc(NFB);
  float* OX   = (float*)alloc((size_t)NN*384*4);
  float* Zb   = (float*)alloc(NFB);
  ushort* xtb4= (ushort*)alloc(NFB2*TT);
  ushort* A1b = (ushort*)alloc(NFB2);
  ushort* A2b = (ushort*)alloc(NFB2);
  ushort* A3b = (ushort*)alloc(NFB2);
  ushort* A4b = (ushort*)alloc(NFB2);
  ushort* HRb = (ushort*)alloc(NFB2);
  ushort* Hab = (ushort*)alloc(NFB2);
  ushort* Hbb = (ushort*)alloc(NFB2);
  ushort* Btx = (ushort*)alloc((size_t)384*768*2);
  ushort* Bth = (ushort*)alloc((size_t)128*384*2);
  ushort* Btd1= (ushort*)alloc((size_t)128*128*2);
  ushort* Btd2= (ushort*)alloc((size_t)128*128*2);
  float* bzc  = (float*)alloc(128*4);
  float* brc  = (float*)alloc(128*4);
  float* bhc  = (float*)alloc(128*4);
  float* dinv4= (float*)alloc((size_t)TT*NN*4);
  int* ccnt   = (int*)alloc((size_t)TT*NB2*NCH2*4);
  int* Abase  = (int*)alloc((size_t)TT*NB2*NCH2*4);
  int* Bbase  = (int*)alloc((size_t)TT*NB2*4);
  int* tot    = (int*)alloc((size_t)TT*NB2*4);
  int* offs4  = (int*)alloc((size_t)TT*(NN+1)*4);
  int2* meta4 = (int2*)alloc((size_t)TT*EE*8);
  // aliases consumed before GRU loop: deg partials in Ha (25.6MB), staging in Hb (12.8MB)
  int* partial = (int*)Ha;
  unsigned* staging = (unsigned*)Hb;

  const int fb2 = (NN*64+255)/256;
  const int sg = (NN+3)/4;
  const int MT = (NN+127)/128;      // 391

  // ---- one-time prep ----
  k_packx<<<(384*768+255)/256,256,0,stream>>>(Wxz,Wxr,Wxh,Whz,Whr,Btx);
  k_packh<<<(128*384+255)/256,256,0,stream>>>(Whh,Bth);
  k_packd<<<64,256,0,stream>>>(Wd1,Btd1);
  k_packd<<<64,256,0,stream>>>(Wd2,Btd2);
  k_bias<<<1,384,0,stream>>>(bxz,bhz,bxr,bhr,bxh,bhh,bzc,brc,bhc);
  k_cast4<<<(TT*NN*FF/4+255)/256,256,0,stream>>>(x, xtb4, TT*NN*FF/4);
  dim3 gh(NCH, NSEG, TT);
  k_hist<<<gh,256,0,stream>>>(ei, partial);
  dim3 gm((NN+255)/256, TT);
  k_merge<<<gm,256,0,stream>>>(partial, dinv4);
  dim3 gc(NCH2, TT);
  k_ccount<<<gc,256,0,stream>>>(ei, ccnt);
  k_cscan<<<TT,128,0,stream>>>(ccnt, Abase, Bbase, tot);
  k_part<<<gc,256,0,stream>>>(ei, Abase, staging);
  dim3 gs(NB2, TT);
  k_sortb<<<gs,256,0,stream>>>(staging, Bbase, tot, dinv4, meta4, offs4);

  float* Hc = Ha; float* Hn = Hb;
  ushort* Hcb = Hab; ushort* Hnb = Hbb;
  for(int t=0;t<TT;++t){
    const ushort* xtb = xtb4 + (size_t)t*NN*FF;
    const int* offs = offs4 + (size_t)t*(NN+1);
    const int2* meta = meta4 + (size_t)t*EE;
    if(t==0){
      k_spmm1<<<sg,256,0,stream>>>(offs,meta, xtb, A1b);
      k_spmm1<<<sg,256,0,stream>>>(offs,meta, A1b, A2b);
      int nwg0 = MT*2;
      k_mgemm<<<nwg0,256,0,stream>>>(xtb,A1b,A2b,nullptr,nullptr,nullptr,
          Btx, nullptr, OX, 384, 768, 2, 2, 0, 0, nwg0, nullptr);
      k_gru0<<<fb2,256,0,stream>>>(OX, bzc, bhc, Hn, Hnb);
    } else {
      k_spmm2<<<sg,256,0,stream>>>(offs,meta, xtb,Hcb, A1b,A3b);
      k_spmm2<<<sg,256,0,stream>>>(offs,meta, A1b,A3b, A2b,A4b);
      int nwg1 = MT*3;
      k_mgemm<<<nwg1,256,0,stream>>>(xtb,A1b,A2b,Hcb,A3b,A4b,
          Btx, nullptr, OX, 768, 768, 3, 1, 0, 0, nwg1, nullptr);
      k_combA<<<fb2,256,0,stream>>>(OX,Hc,bzc,brc,Zb,HRb);
      k_spmm1<<<sg,256,0,stream>>>(offs,meta, HRb, A3b);
      k_spmm1<<<sg,256,0,stream>>>(offs,meta, A3b, A4b);
      int nwg3 = MT;
      k_mgemm<<<nwg3,256,0,stream>>>(HRb,A3b,A4b,nullptr,nullptr,nullptr,
          Bth, nullptr, OX, 384, 384, 1, 1, 256, 1, nwg3, nullptr);
      float* hout2 = (t==TT-1) ? (out + (size_t)NN*FF) : nullptr;
      k_combB<<<fb2,256,0,stream>>>(OX,Zb,Hc,bhc,Hn,Hnb,hout2);
    }
    float* tmp=Hc; Hc=Hn; Hn=tmp;
    ushort* tb=Hcb; Hcb=Hnb; Hnb=tb;
  }
  // decoder: relu(H@Wd1+bd1)@Wd2+bd2  (MFMA bf16; A1b as bf16 temp)
  k_mgemm<<<MT,256,0,stream>>>(Hcb,nullptr,nullptr,nullptr,nullptr,nullptr,
      Btd1, A1b, nullptr, 128, 128, 1, 1, 0, 2, MT, bd1);
  k_mgemm<<<MT,256,0,stream>>>(A1b,nullptr,nullptr,nullptr,nullptr,nullptr,
      Btd2, nullptr, out, 128, 128, 1, 1, 0, 3, MT, bd2);
}

// Round 17
// 1213.589 us; speedup vs baseline: 2.2939x; 1.0301x over previous
//
#include <hip/hip_runtime.h>
#include <math.h>

#define NN 50000
#define TT 4
#define FF 128
#define EE 800000
#define NSEG 4      // node-space segments for LDS deg histogram
#define BINSEG 12500
#define NCH 32      // edge chunks for deg histogram
#define CHUNK 25000
#define NCH2 128    // edge chunks for partition
#define CH2 6250    // EE/NCH2
#define NB2 64      // coarse dst buckets
#define CB 782      // nodes per bucket (64*782=50048 >= NN)
#define NSEG2 16    // src segments for within-row quantile sort
#define SEGW 3125   // 50000/16
#define SBINS (CB*NSEG2)   // 12512
#define SCHUNK 49          // ceil(SBINS/256)
#define SMAX 13312  // LDS sort capacity per bucket (mean 12512, +7 sigma; 52 KB)

typedef __attribute__((ext_vector_type(8))) short bf8_t;
typedef __attribute__((ext_vector_type(4))) float f4_t;
typedef __attribute__((ext_vector_type(8))) ushort us8;

__device__ inline ushort f2bf(float f){
  union { float f; unsigned u; } v; v.f = f;
  unsigned u = v.u;
  unsigned r = (u + 0x7fff + ((u>>16)&1)) >> 16;  // RNE
  return (ushort)r;
}
__device__ inline float lo16(unsigned u){ union{unsigned u;float f;}v; v.u=u<<16; return v.f; }
__device__ inline float hi16(unsigned u){ union{unsigned u;float f;}v; v.u=u&0xffff0000u; return v.f; }
__device__ inline unsigned packbf(float x, float y){
  return (unsigned)f2bf(x) | ((unsigned)f2bf(y)<<16);
}
__device__ inline float sigm(float x){ return 1.f/(1.f+expf(-x)); }

// ---------------- utility ----------------
__global__ void k_cast4(const float* __restrict__ in, ushort* __restrict__ outp, int n4){
  int i = blockIdx.x*256 + threadIdx.x;
  if(i<n4){
    float4 v = ((const float4*)in)[i];
    ushort4 o; o.x=f2bf(v.x); o.y=f2bf(v.y); o.z=f2bf(v.z); o.w=f2bf(v.w);
    ((ushort4*)outp)[i]=o;
  }
}
__global__ void k_bias(const float* bxz, const float* bhz, const float* bxr,
                       const float* bhr, const float* bxh, const float* bhh,
                       float* __restrict__ bz, float* __restrict__ br, float* __restrict__ bh){
  int i = threadIdx.x;  // 384 threads
  int c = i & 127, s = i >> 7;
  if(s==0) bz[c]=bxz[c]+bhz[c];
  else if(s==1) br[c]=bxr[c]+bhr[c];
  else bh[c]=bxh[c]+bhh[c];
}

// ---------- deg (src) histogram via LDS segments -> dinv ----------
__global__ __launch_bounds__(256) void k_hist(const int* __restrict__ ei,
                                              int* __restrict__ part){
  int c = blockIdx.x, seg = blockIdx.y, t = blockIdx.z;
  const int* keys = ei + (size_t)t*2*EE;   // src array
  __shared__ int h[BINSEG];
  for(int i=threadIdx.x;i<BINSEG;i+=256) h[i]=0;
  __syncthreads();
  int base = seg*BINSEG;
  int e0 = c*CHUNK, e1 = e0+CHUNK;
  for(int e=e0+threadIdx.x; e<e1; e+=256){
    int k = keys[e] - base;
    if((unsigned)k < (unsigned)BINSEG) atomicAdd(&h[k],1);
  }
  __syncthreads();
  int* dp = part + ((((size_t)t)*NSEG + seg)*NCH + c)*BINSEG;
  for(int i=threadIdx.x;i<BINSEG;i+=256) dp[i]=h[i];
}
__global__ void k_merge(const int* __restrict__ part, float* __restrict__ dinv4){
  int t = blockIdx.y;
  int n = blockIdx.x*256 + threadIdx.x;
  if(n>=NN) return;
  int seg = n / BINSEG, b = n - seg*BINSEG;
  const int* p = part + ((((size_t)t)*NSEG + seg)*NCH)*BINSEG + b;
  int s = 0;
  #pragma unroll
  for(int c=0;c<NCH;++c) s += p[(size_t)c*BINSEG];
  dinv4[(size_t)t*NN + n] = s>0 ? rsqrtf((float)s) : 0.f;
}

// ---------- coarse bucket counts per (t, chunk) ----------
__global__ __launch_bounds__(256) void k_ccount(const int* __restrict__ ei,
                                                int* __restrict__ ccnt){
  int c = blockIdx.x, t = blockIdx.y;
  const int* dst = ei + (size_t)t*2*EE + EE;
  __shared__ int h[NB2];
  if(threadIdx.x<NB2) h[threadIdx.x]=0;
  __syncthreads();
  int e0 = c*CH2, e1 = e0+CH2;
  for(int e=e0+threadIdx.x; e<e1; e+=256) atomicAdd(&h[dst[e]/CB],1);
  __syncthreads();
  if(threadIdx.x<NB2) ccnt[((size_t)t*NB2 + threadIdx.x)*NCH2 + c] = h[threadIdx.x];
}
__global__ __launch_bounds__(128) void k_cscan(const int* __restrict__ ccnt,
                        int* __restrict__ Abase, int* __restrict__ Bbase,
                        int* __restrict__ tot){
  int t = blockIdx.x, tid = threadIdx.x;
  __shared__ int st[NB2];
  __shared__ int sb[NB2];
  const int* cc = ccnt + (size_t)t*NB2*NCH2;
  if(tid<NB2){
    int s=0;
    for(int c=0;c<NCH2;++c) s += cc[tid*NCH2+c];
    st[tid]=s;
  }
  __syncthreads();
  if(tid==0){
    int run=0;
    for(int b=0;b<NB2;++b){ sb[b]=run; run+=st[b]; }
  }
  __syncthreads();
  if(tid<NB2){
    Bbase[t*NB2+tid]=sb[tid];
    tot[t*NB2+tid]=st[tid];
    int run = sb[tid];
    int* ab = Abase + ((size_t)t*NB2 + tid)*NCH2;
    for(int c=0;c<NCH2;++c){ ab[c]=run; run+=cc[tid*NCH2+c]; }
  }
}
__global__ __launch_bounds__(256) void k_part(const int* __restrict__ ei,
                        const int* __restrict__ Abase, unsigned* __restrict__ staging){
  int c = blockIdx.x, t = blockIdx.y;
  const int* src = ei + (size_t)t*2*EE;
  const int* dst = src + EE;
  unsigned* stg = staging + (size_t)t*EE;
  const int* ab = Abase + (size_t)t*NB2*NCH2;
  __shared__ int h[NB2];
  if(threadIdx.x<NB2) h[threadIdx.x]=0;
  __syncthreads();
  int e0 = c*CH2, e1 = e0+CH2;
  for(int e=e0+threadIdx.x; e<e1; e+=256){
    int s=src[e], d=dst[e];
    int b = d/CB, dl = d - b*CB;
    int r = atomicAdd(&h[b],1);
    stg[ab[b*NCH2 + c] + r] = ((unsigned)dl<<16) | (unsigned)s;
  }
}
// per-bucket LDS counting sort by (dstLocal, src/SEGW) -> meta + offs
__global__ __launch_bounds__(256) void k_sortb(const unsigned* __restrict__ staging,
                        const int* __restrict__ Bbase, const int* __restrict__ tot,
                        const float* __restrict__ dinv4, int2* __restrict__ meta4,
                        int* __restrict__ offs4){
  int b = blockIdx.x, t = blockIdx.y, tid = threadIdx.x;
  __shared__ int cnt[SBINS];
  __shared__ int sums[256];
  __shared__ unsigned sorted[SMAX];
  int sA = Bbase[t*NB2+b];
  int nb = tot[t*NB2+b];
  const unsigned* stg = staging + (size_t)t*EE + sA;
  const float* dinv = dinv4 + (size_t)t*NN;
  int* offs = offs4 + (size_t)t*(NN+1);
  int2* meta = meta4 + (size_t)t*EE + sA;
  for(int i=tid;i<SBINS;i+=256) cnt[i]=0;
  __syncthreads();
  for(int i=tid;i<nb;i+=256){
    unsigned v = stg[i];
    int key = (int)(v>>16)*NSEG2 + (int)(v&0xFFFF)/SEGW;
    atomicAdd(&cnt[key],1);
  }
  __syncthreads();
  int base = tid*SCHUNK;
  int s0 = 0;
  for(int j=0;j<SCHUNK;++j){ int idx=base+j; if(idx<SBINS) s0+=cnt[idx]; }
  sums[tid]=s0; __syncthreads();
  for(int off=1;off<256;off<<=1){
    int v=(tid>=off)?sums[tid-off]:0; __syncthreads();
    sums[tid]+=v; __syncthreads();
  }
  int run = sums[tid]-s0;
  for(int j=0;j<SCHUNK;++j){
    int idx=base+j;
    if(idx<SBINS){ int c=cnt[idx]; cnt[idx]=run; run+=c; }
  }
  __syncthreads();
  for(int dl=tid; dl<CB; dl+=256){
    int n = b*CB + dl;
    if(n<=NN) offs[n] = sA + cnt[dl*NSEG2];
  }
  __syncthreads();
  for(int i=tid;i<nb;i+=256){
    unsigned v = stg[i];
    int key = (int)(v>>16)*NSEG2 + (int)(v&0xFFFF)/SEGW;
    int r = atomicAdd(&cnt[key],1);
    if(r<SMAX) sorted[r]=v;
  }
  __syncthreads();
  for(int i=tid;i<nb;i+=256){
    if(i>=SMAX) break;
    unsigned v = sorted[i];
    int s = v & 0xFFFF, d = b*CB + (v>>16);
    int2 m; m.x = s; m.y = __float_as_int(-dinv[s]*dinv[d]);
    meta[i]=m;
  }
}

// -------- fused dual-input bf16 gather-SpMM (4-edge unroll, plain ld/st) --------
__global__ void k_spmm2(const int* __restrict__ offs, const int2* __restrict__ meta,
                        const ushort* __restrict__ Xa, const ushort* __restrict__ Xb,
                        ushort* __restrict__ outA, ushort* __restrict__ outB){
  int wid = threadIdx.x>>6, lane = threadIdx.x&63;
  int row = blockIdx.x*4+wid;
  if(row>=NN) return;
  int beg = offs[row], end = offs[row+1];
  const unsigned* XA = (const unsigned*)Xa;
  const unsigned* XB = (const unsigned*)Xb;
  float ax=0.f, ay=0.f, bx=0.f, by=0.f;
  int e = beg;
  for(; e+3<end; e+=4){
    int2 p0=meta[e+0], p1=meta[e+1], p2=meta[e+2], p3=meta[e+3];
    float w0=__int_as_float(p0.y), w1=__int_as_float(p1.y);
    float w2=__int_as_float(p2.y), w3=__int_as_float(p3.y);
    unsigned a0=XA[p0.x*64+lane], a1=XA[p1.x*64+lane], a2=XA[p2.x*64+lane], a3=XA[p3.x*64+lane];
    unsigned b0=XB[p0.x*64+lane], b1=XB[p1.x*64+lane], b2=XB[p2.x*64+lane], b3=XB[p3.x*64+lane];
    ax=fmaf(w0,lo16(a0),ax); ay=fmaf(w0,hi16(a0),ay);
    ax=fmaf(w1,lo16(a1),ax); ay=fmaf(w1,hi16(a1),ay);
    ax=fmaf(w2,lo16(a2),ax); ay=fmaf(w2,hi16(a2),ay);
    ax=fmaf(w3,lo16(a3),ax); ay=fmaf(w3,hi16(a3),ay);
    bx=fmaf(w0,lo16(b0),bx); by=fmaf(w0,hi16(b0),by);
    bx=fmaf(w1,lo16(b1),bx); by=fmaf(w1,hi16(b1),by);
    bx=fmaf(w2,lo16(b2),bx); by=fmaf(w2,hi16(b2),by);
    bx=fmaf(w3,lo16(b3),bx); by=fmaf(w3,hi16(b3),by);
  }
  for(; e<end; ++e){
    int2 pm=meta[e]; float w=__int_as_float(pm.y);
    unsigned a=XA[pm.x*64+lane], b=XB[pm.x*64+lane];
    ax=fmaf(w,lo16(a),ax); ay=fmaf(w,hi16(a),ay);
    bx=fmaf(w,lo16(b),bx); by=fmaf(w,hi16(b),by);
  }
  int oi = row*64+lane;
  ((unsigned*)outA)[oi] = packbf(ax, ay);
  ((unsigned*)outB)[oi] = packbf(bx, by);
}
__global__ void k_spmm1(const int* __restrict__ offs, const int2* __restrict__ meta,
                        const ushort* __restrict__ Xa, ushort* __restrict__ outA){
  int wid = threadIdx.x>>6, lane = threadIdx.x&63;
  int row = blockIdx.x*4+wid;
  if(row>=NN) return;
  int beg = offs[row], end = offs[row+1];
  const unsigned* XA = (const unsigned*)Xa;
  float ax=0.f, ay=0.f;
  int e = beg;
  for(; e+3<end; e+=4){
    int2 p0=meta[e+0], p1=meta[e+1], p2=meta[e+2], p3=meta[e+3];
    float w0=__int_as_float(p0.y), w1=__int_as_float(p1.y);
    float w2=__int_as_float(p2.y), w3=__int_as_float(p3.y);
    unsigned a0=XA[p0.x*64+lane], a1=XA[p1.x*64+lane], a2=XA[p2.x*64+lane], a3=XA[p3.x*64+lane];
    ax=fmaf(w0,lo16(a0),ax); ay=fmaf(w0,hi16(a0),ay);
    ax=fmaf(w1,lo16(a1),ax); ay=fmaf(w1,hi16(a1),ay);
    ax=fmaf(w2,lo16(a2),ax); ay=fmaf(w2,hi16(a2),ay);
    ax=fmaf(w3,lo16(a3),ax); ay=fmaf(w3,hi16(a3),ay);
  }
  for(; e<end; ++e){
    int2 pm=meta[e]; float w=__int_as_float(pm.y);
    unsigned a=XA[pm.x*64+lane];
    ax=fmaf(w,lo16(a),ax); ay=fmaf(w,hi16(a),ay);
  }
  ((unsigned*)outA)[row*64+lane] = packbf(ax, ay);
}

// ---------------- MFMA bf16 GEMM with register-staged K-prefetch ----------------
// modes: 0 = fp32 store Cf[r*384+coloff+c]  (GRU main)
//        1 = fp32 beta-accumulate Cf[r*384+coloff+c]  (HR path)
//        2 = bias+relu -> bf16 Cb[r*128+c]  (decoder 1)
//        3 = bias -> fp32 Cf[r*128+c]       (decoder 2)
__global__ __launch_bounds__(256) void k_mgemm(
    const ushort* __restrict__ A0, const ushort* __restrict__ A1,
    const ushort* __restrict__ A2, const ushort* __restrict__ A3,
    const ushort* __restrict__ A4, const ushort* __restrict__ A5,
    const ushort* __restrict__ Bt, ushort* __restrict__ Cb, float* __restrict__ Cf,
    int K, int ldb, int ngrp, int bnstep, int coloff, int mode, int nwg,
    const float* __restrict__ bias)
{
  __shared__ ushort As[128*64];
  __shared__ ushort Bs[128*64];
  int tid = threadIdx.x;
  int lane = tid & 63;
  int wid = tid >> 6;
  int wr = (wid>>1)*64, wc = (wid&1)*64;
  int bid = blockIdx.x;
  int q = nwg >> 3, r = nwg & 7;
  int xs = bid & 7, j = bid >> 3;
  int logical = xs*q + ((xs<r)?xs:r) + j;
  int bm = logical / ngrp;
  int bn = (logical - bm*ngrp) * bnstep;
  f4_t acc[4][4] = {};
  int srow = tid>>3, sc = tid&7;
  int lr = lane&15, lk = lane>>4;
  int nkt = K>>6;
  // per-thread constants across K-steps
  size_t aro[4]; size_t bro[4]; int wos[4];
  #pragma unroll
  for(int p=0;p<4;++p){
    int rr = srow + p*32;
    int gr = bm*128 + rr; if(gr>=NN) gr=NN-1;
    aro[p] = (size_t)gr*128 + sc*8;
    bro[p] = (size_t)(bn*128 + rr)*ldb + sc*8;
    wos[p] = (rr*128 + ((sc*16) ^ ((rr&7)<<4))) >> 1;
  }
  us8 avr[4], bvr[4];
  // preload K-tile 0 (k0=0 -> chunk A0, kloc 0)
  #pragma unroll
  for(int p=0;p<4;++p){
    avr[p] = *(const us8*)(A0 + aro[p]);
    bvr[p] = *(const us8*)(Bt + bro[p]);
  }
  for(int kt=0; kt<nkt; ++kt){
    // commit staged registers to LDS
    #pragma unroll
    for(int p=0;p<4;++p){
      *(us8*)(As + wos[p]) = avr[p];
      *(us8*)(Bs + wos[p]) = bvr[p];
    }
    __syncthreads();
    // issue next K-tile's global loads; latency overlaps the MFMA phase below
    if(kt+1 < nkt){
      int k0 = (kt+1)<<6;
      const ushort* Ac = (k0<128)?A0:(k0<256)?A1:(k0<384)?A2:(k0<512)?A3:(k0<640)?A4:A5;
      int kloc = k0 & 127;
      #pragma unroll
      for(int p=0;p<4;++p){
        avr[p] = *(const us8*)(Ac + aro[p] + kloc);
        bvr[p] = *(const us8*)(Bt + bro[p] + k0);
      }
    }
    #pragma unroll
    for(int kk=0;kk<2;++kk){
      bf8_t af[4], bfr[4];
      int co = kk*64 + lk*16;
      #pragma unroll
      for(int m=0;m<4;++m){
        int Ra = wr + m*16 + lr;
        af[m]  = *(const bf8_t*)(As + ((Ra*128 + (co ^ ((Ra&7)<<4)))>>1));
        int Rb = wc + m*16 + lr;
        bfr[m] = *(const bf8_t*)(Bs + ((Rb*128 + (co ^ ((Rb&7)<<4)))>>1));
      }
      #pragma unroll
      for(int m=0;m<4;++m)
        #pragma unroll
        for(int n=0;n<4;++n)
          acc[m][n] = __builtin_amdgcn_mfma_f32_16x16x32_bf16(af[m], bfr[n], acc[m][n], 0,0,0);
    }
    __syncthreads();
  }
  int row0 = bm*128 + wr + lk*4;
  int col0 = bn*128 + wc + lr;
  #pragma unroll
  for(int m=0;m<4;++m){
    #pragma unroll
    for(int i=0;i<4;++i){
      int rI = row0 + m*16 + i;
      if(rI<NN){
        if(mode<=1){
          float* cp = Cf + (size_t)rI*384 + coloff + col0;
          #pragma unroll
          for(int n=0;n<4;++n){
            float v = acc[m][n][i];
            if(mode==1) v += cp[n*16];
            cp[n*16] = v;
          }
        } else if(mode==2){
          #pragma unroll
          for(int n=0;n<4;++n){
            int c = col0 + n*16;
            float v = acc[m][n][i] + bias[c];
            Cb[(size_t)rI*128 + c] = f2bf(fmaxf(v,0.f));
          }
        } else {
          #pragma unroll
          for(int n=0;n<4;++n){
            int c = col0 + n*16;
            Cf[(size_t)rI*128 + c] = acc[m][n][i] + bias[c];
          }
        }
      }
    }
  }
}

// Z = sigmoid(OX[:,0:128]+bz); HRb = bf16(H * sigmoid(OX[:,128:256]+br))   (2 elems/thread)
__global__ void k_combA(const float* __restrict__ OX, const float* __restrict__ H,
                        const float* __restrict__ bz, const float* __restrict__ br,
                        float* __restrict__ Z, ushort* __restrict__ HRb){
  int i = blockIdx.x*256 + threadIdx.x;
  if(i>=NN*64) return;
  int r = i>>6, c2 = (i&63)*2;
  float2 zv2 = *(const float2*)(OX + (size_t)r*384 + c2);
  float2 rv2 = *(const float2*)(OX + (size_t)r*384 + 128 + c2);
  float2 h   = ((const float2*)H)[i];
  float z0 = sigm(zv2.x + bz[c2]),   z1 = sigm(zv2.y + bz[c2+1]);
  float r0 = sigm(rv2.x + br[c2]),   r1 = sigm(rv2.y + br[c2+1]);
  float2 zz; zz.x=z0; zz.y=z1;
  ((float2*)Z)[i] = zz;
  ((unsigned*)HRb)[i] = packbf(h.x*r0, h.y*r1);
}
// Htilde = tanh(OX[:,256:384]+bh); Hnew = Z*H + (1-Z)*Htilde   (2 elems/thread)
__global__ void k_combB(const float* __restrict__ OX, const float* __restrict__ Z,
                        const float* __restrict__ H, const float* __restrict__ bh,
                        float* __restrict__ Hn, ushort* __restrict__ Hnb,
                        float* __restrict__ Hout2){
  int i = blockIdx.x*256 + threadIdx.x;
  if(i>=NN*64) return;
  int r = i>>6, c2 = (i&63)*2;
  float2 hv = *(const float2*)(OX + (size_t)r*384 + 256 + c2);
  float2 z  = ((const float2*)Z)[i];
  float2 h  = ((const float2*)H)[i];
  float t0 = tanhf(hv.x + bh[c2]);
  float t1 = tanhf(hv.y + bh[c2+1]);
  float hn0 = z.x*h.x + (1.f-z.x)*t0;
  float hn1 = z.y*h.y + (1.f-z.y)*t1;
  float2 hn; hn.x=hn0; hn.y=hn1;
  ((float2*)Hn)[i] = hn;
  ((unsigned*)Hnb)[i] = packbf(hn0, hn1);
  if(Hout2) ((float2*)Hout2)[i] = hn;
}
// t=0 (H==0): Hn = (1 - sigm(OXz+bz)) * tanh(OXh+bh)   (2 elems/thread)
__global__ void k_gru0(const float* __restrict__ OX, const float* __restrict__ bz,
                       const float* __restrict__ bh, float* __restrict__ Hn,
                       ushort* __restrict__ Hnb){
  int i = blockIdx.x*256 + threadIdx.x;
  if(i>=NN*64) return;
  int r = i>>6, c2 = (i&63)*2;
  float2 zv = *(const float2*)(OX + (size_t)r*384 + c2);
  float2 hv = *(const float2*)(OX + (size_t)r*384 + 256 + c2);
  float z0 = sigm(zv.x + bz[c2]), z1 = sigm(zv.y + bz[c2+1]);
  float t0 = tanhf(hv.x + bh[c2]);
  float t1 = tanhf(hv.y + bh[c2+1]);
  float hn0 = (1.f-z0)*t0, hn1 = (1.f-z1)*t1;
  float2 hn; hn.x=hn0; hn.y=hn1;
  ((float2*)Hn)[i] = hn;
  ((unsigned*)Hnb)[i] = packbf(hn0, hn1);
}

// pack x-side weights, REBASED: chunks [X:(W0-W2), U1:W1, U2:2*W2]
__global__ void k_packx(const float* __restrict__ Wxz, const float* __restrict__ Wxr,
                        const float* __restrict__ Wxh, const float* __restrict__ Whz,
                        const float* __restrict__ Whr, ushort* __restrict__ Bt){
  int i = blockIdx.x*256 + threadIdx.x;
  if(i>=384*768) return;
  int c = i/768, k = i - c*768;
  int g = c>>7, j = c&127;
  int kb = k>>7, kk = k&127;
  float v;
  int e = kk*128 + j;
  if(kb<3){
    const float* W = (g==0)?Wxz:((g==1)?Wxr:Wxh);
    v = (kb==0) ? (W[e] - W[2*16384 + e]) : (kb==1 ? W[16384 + e] : 2.f*W[2*16384 + e]);
  } else if(g<2){
    const float* W = (g==0)?Whz:Whr;
    int kb2 = kb-3;
    v = (kb2==0) ? (W[e] - W[2*16384 + e]) : (kb2==1 ? W[16384 + e] : 2.f*W[2*16384 + e]);
  } else v = 0.f;
  Bt[i] = f2bf(v);
}
__global__ void k_packh(const float* __restrict__ Whh, ushort* __restrict__ Bt){
  int i = blockIdx.x*256 + threadIdx.x;
  if(i>=128*384) return;
  int c = i/384, k = i - c*384;
  int kb = k>>7, kk = k&127;
  int e = kk*128 + c;
  float v = (kb==0) ? (Whh[e] - Whh[2*16384 + e]) : (kb==1 ? Whh[16384 + e] : 2.f*Whh[2*16384 + e]);
  Bt[i] = f2bf(v);
}
// decoder weight: Bt[c][k] = W[k][c], 128x128
__global__ void k_packd(const float* __restrict__ W, ushort* __restrict__ Bt){
  int i = blockIdx.x*256 + threadIdx.x;
  if(i>=128*128) return;
  int c = i>>7, k = i&127;
  Bt[i] = f2bf(W[k*128 + c]);
}

extern "C" void kernel_launch(void* const* d_in, const int* in_sizes, int n_in,
                              void* d_out, int out_size, void* d_ws, size_t ws_size,
                              hipStream_t stream) {
  const float* x   = (const float*)d_in[0];
  const int*   ei  = (const int*)d_in[1];
  const float* Wxz = (const float*)d_in[2];
  const float* Whz = (const float*)d_in[3];
  const float* Wxr = (const float*)d_in[4];
  const float* Whr = (const float*)d_in[5];
  const float* Wxh = (const float*)d_in[6];
  const float* Whh = (const float*)d_in[7];
  const float* bxz = (const float*)d_in[8];
  const float* bhz = (const float*)d_in[9];
  const float* bxr = (const float*)d_in[10];
  const float* bhr = (const float*)d_in[11];
  const float* bxh = (const float*)d_in[12];
  const float* bhh = (const float*)d_in[13];
  const float* Wd1 = (const float*)d_in[14];
  const float* bd1 = (const float*)d_in[15];
  const float* Wd2 = (const float*)d_in[16];
  const float* bd2 = (const float*)d_in[17];
  float* out = (float*)d_out;

  char* p = (char*)d_ws;
  auto alloc = [&](size_t bytes)->void*{ void* r = (void*)p; p += (bytes+255)&~(size_t)255; return r; };
  const size_t NFB  = (size_t)NN*FF*4;
  const size_t NFB2 = (size_t)NN*FF*2;
  float* Ha   = (float*)alloc(NFB);
  float* Hb   = (float*)alloc(NFB);
  float* OX   = (float*)alloc((size_t)NN*384*4);
  float* Zb   = (float*)alloc(NFB);
  ushort* xtb4= (ushort*)alloc(NFB2*TT);
  ushort* A1b = (ushort*)alloc(NFB2);
  ushort* A2b = (ushort*)alloc(NFB2);
  ushort* A3b = (ushort*)alloc(NFB2);
  ushort* A4b = (ushort*)alloc(NFB2);
  ushort* HRb = (ushort*)alloc(NFB2);
  ushort* Hab = (ushort*)alloc(NFB2);
  ushort* Hbb = (ushort*)alloc(NFB2);
  ushort* Btx = (ushort*)alloc((size_t)384*768*2);
  ushort* Bth = (ushort*)alloc((size_t)128*384*2);
  ushort* Btd1= (ushort*)alloc((size_t)128*128*2);
  ushort* Btd2= (ushort*)alloc((size_t)128*128*2);
  float* bzc  = (float*)alloc(128*4);
  float* brc  = (float*)alloc(128*4);
  float* bhc  = (float*)alloc(128*4);
  float* dinv4= (float*)alloc((size_t)TT*NN*4);
  int* ccnt   = (int*)alloc((size_t)TT*NB2*NCH2*4);
  int* Abase  = (int*)alloc((size_t)TT*NB2*NCH2*4);
  int* Bbase  = (int*)alloc((size_t)TT*NB2*4);
  int* tot    = (int*)alloc((size_t)TT*NB2*4);
  int* offs4  = (int*)alloc((size_t)TT*(NN+1)*4);
  int2* meta4 = (int2*)alloc((size_t)TT*EE*8);
  // aliases consumed before GRU loop: deg partials in Ha (25.6MB), staging in Hb (12.8MB)
  int* partial = (int*)Ha;
  unsigned* staging = (unsigned*)Hb;

  const int fb2 = (NN*64+255)/256;
  const int sg = (NN+3)/4;
  const int MT = (NN+127)/128;      // 391

  // ---- one-time prep ----
  k_packx<<<(384*768+255)/256,256,0,stream>>>(Wxz,Wxr,Wxh,Whz,Whr,Btx);
  k_packh<<<(128*384+255)/256,256,0,stream>>>(Whh,Bth);
  k_packd<<<64,256,0,stream>>>(Wd1,Btd1);
  k_packd<<<64,256,0,stream>>>(Wd2,Btd2);
  k_bias<<<1,384,0,stream>>>(bxz,bhz,bxr,bhr,bxh,bhh,bzc,brc,bhc);
  k_cast4<<<(TT*NN*FF/4+255)/256,256,0,stream>>>(x, xtb4, TT*NN*FF/4);
  dim3 gh(NCH, NSEG, TT);
  k_hist<<<gh,256,0,stream>>>(ei, partial);
  dim3 gm((NN+255)/256, TT);
  k_merge<<<gm,256,0,stream>>>(partial, dinv4);
  dim3 gc(NCH2, TT);
  k_ccount<<<gc,256,0,stream>>>(ei, ccnt);
  k_cscan<<<TT,128,0,stream>>>(ccnt, Abase, Bbase, tot);
  k_part<<<gc,256,0,stream>>>(ei, Abase, staging);
  dim3 gs(NB2, TT);
  k_sortb<<<gs,256,0,stream>>>(staging, Bbase, tot, dinv4, meta4, offs4);

  float* Hc = Ha; float* Hn = Hb;
  ushort* Hcb = Hab; ushort* Hnb = Hbb;
  for(int t=0;t<TT;++t){
    const ushort* xtb = xtb4 + (size_t)t*NN*FF;
    const int* offs = offs4 + (size_t)t*(NN+1);
    const int2* meta = meta4 + (size_t)t*EE;
    if(t==0){
      k_spmm1<<<sg,256,0,stream>>>(offs,meta, xtb, A1b);
      k_spmm1<<<sg,256,0,stream>>>(offs,meta, A1b, A2b);
      int nwg0 = MT*2;
      k_mgemm<<<nwg0,256,0,stream>>>(xtb,A1b,A2b,nullptr,nullptr,nullptr,
          Btx, nullptr, OX, 384, 768, 2, 2, 0, 0, nwg0, nullptr);
      k_gru0<<<fb2,256,0,stream>>>(OX, bzc, bhc, Hn, Hnb);
    } else {
      k_spmm2<<<sg,256,0,stream>>>(offs,meta, xtb,Hcb, A1b,A3b);
      k_spmm2<<<sg,256,0,stream>>>(offs,meta, A1b,A3b, A2b,A4b);
      int nwg1 = MT*3;
      k_mgemm<<<nwg1,256,0,stream>>>(xtb,A1b,A2b,Hcb,A3b,A4b,
          Btx, nullptr, OX, 768, 768, 3, 1, 0, 0, nwg1, nullptr);
      k_combA<<<fb2,256,0,stream>>>(OX,Hc,bzc,brc,Zb,HRb);
      k_spmm1<<<sg,256,0,stream>>>(offs,meta, HRb, A3b);
      k_spmm1<<<sg,256,0,stream>>>(offs,meta, A3b, A4b);
      int nwg3 = MT;
      k_mgemm<<<nwg3,256,0,stream>>>(HRb,A3b,A4b,nullptr,nullptr,nullptr,
          Bth, nullptr, OX, 384, 384, 1, 1, 256, 1, nwg3, nullptr);
      float* hout2 = (t==TT-1) ? (out + (size_t)NN*FF) : nullptr;
      k_combB<<<fb2,256,0,stream>>>(OX,Zb,Hc,bhc,Hn,Hnb,hout2);
    }
    float* tmp=Hc; Hc=Hn; Hn=tmp;
    ushort* tb=Hcb; Hcb=Hnb; Hnb=tb;
  }
  // decoder: relu(H@Wd1+bd1)@Wd2+bd2  (MFMA bf16; A1b as bf16 temp)
  k_mgemm<<<MT,256,0,stream>>>(Hcb,nullptr,nullptr,nullptr,nullptr,nullptr,
      Btd1, A1b, nullptr, 128, 128, 1, 1, 0, 2, MT, bd1);
  k_mgemm<<<MT,256,0,stream>>>(A1b,nullptr,nullptr,nullptr,nullptr,nullptr,
      Btd2, nullptr, out, 128, 128, 1, 1, 0, 3, MT, bd2);
}